// Round 6
// baseline (158.232 us; speedup 1.0000x reference)
//
#include <hip/hip_runtime.h>
#include <stdint.h>
#include <math.h>

typedef unsigned int u32;
typedef unsigned long long u64;

#define NN_ 28800
#define MM_ 64
#define BB_ 16
#define XROW_ 25
#define POS_CAP_ 128u
#define BATCH_ 256u

struct Keys { u32 k[BB_][4]; };

// ---------------- threefry2x32 (JAX-exact), host+device ----------------
__host__ __device__ __forceinline__ u32 rotl32(u32 v, u32 r){ return (v<<r)|(v>>(32u-r)); }

__host__ __device__ __forceinline__ void tf2x32(u32 k0, u32 k1, u32 x0, u32 x1, u32& y0, u32& y1){
  u32 ks2 = k0 ^ k1 ^ 0x1BD11BDAu;
  x0 += k0; x1 += k1;
#define TFR(r) { x0 += x1; x1 = rotl32(x1,(r)); x1 ^= x0; }
  TFR(13) TFR(15) TFR(26) TFR(6)   x0 += k1;  x1 += ks2 + 1u;
  TFR(17) TFR(29) TFR(16) TFR(24)  x0 += ks2; x1 += k0  + 2u;
  TFR(13) TFR(15) TFR(26) TFR(6)   x0 += k0;  x1 += k1  + 3u;
  TFR(17) TFR(29) TFR(16) TFR(24)  x0 += k1;  x1 += ks2 + 4u;
  TFR(13) TFR(15) TFR(26) TFR(6)   x0 += ks2; x1 += k0  + 5u;
#undef TFR
  y0 = x0; y1 = x1;
}

// ---------------- anchors: pure-float, bit-exact vs numpy ----------------
__device__ __forceinline__ void anchor_from(int a, int cell,
                                            float& ox1, float& oy1, float& ox2, float& oy2){
  #pragma clang fp contract(off)
  int w = cell & 63;
  int h = cell >> 6;
  int p = (a >= 6) ? 2 : ((a >= 3) ? 1 : 0);
  int q = a - p*3;
  float sf = (p==0) ? 128.0f : ((p==1) ? 256.0f : 512.0f);
  const float SQH = 0.70710678118654752440f;
  const float SQ2 = 1.41421356237309514547f;
  float cw = (q==0) ? SQH : ((q==1) ? 1.0f : SQ2);
  float ch = (q==0) ? SQ2 : ((q==1) ? 1.0f : SQH);
  float hx = (sf*cw) * 0.5f;
  float hy = (sf*ch) * 0.5f;
  float cx = ((float)w + 0.5f) * 16.0f;
  float cy = ((float)h + 0.5f) * 16.0f;
  float X1 = (cx - hx) / 1024.0f;
  float Y1 = (cy - hy) / 800.0f;
  float X2 = (cx + hx) / 1024.0f;
  float Y2 = (cy + hy) / 800.0f;
  bool valid = (X1 > 0.0f) && (Y1 > 0.0f) && (X2 < 1.0f) && (Y2 < 1.0f);
  ox1 = valid ? X1 : 0.0f;
  oy1 = valid ? Y1 : 0.0f;
  ox2 = valid ? X2 : 0.0f;
  oy2 = valid ? Y2 : 0.0f;
}

__device__ __forceinline__ float rdlane(float v, int k){
  return __int_as_float(__builtin_amdgcn_readlane(__float_as_int(v), k));
}

// ---------------- K1: transposed (lane = gt); no DS/atomics in inner loop ----------------
__global__ __launch_bounds__(128, 6) void k_main(const float* __restrict__ x, Keys keys,
                                                 u64* __restrict__ bestkey,
                                                 u32* __restrict__ rpv, u32* __restrict__ rnv,
                                                 u32* __restrict__ counts, u32* __restrict__ hist){
  #pragma clang fp contract(off)
  int tid = threadIdx.x;          // 0..127 (2 waves)
  int lane = tid & 63;
  int wid = tid >> 6;
  int b = blockIdx.y;
  int cbase = (blockIdx.x*2 + wid)*64;     // this wave's 64-anchor chunk

  // lane j holds gt j in registers
  const float* gp = x + (b*MM_ + lane)*XROW_ + 21;
  float gx1 = gp[0], gy1 = gp[1], gx2 = gp[2], gy2 = gp[3];
  float garea = (gx2-gx1)*(gy2-gy1);       // exact reference op order

  // lane k holds anchor (cbase+k)'s box
  int ia = cbase + lane;
  int a = ia % 9, cell = ia / 9;
  float ax1,ay1,ax2,ay2;
  anchor_from(a, cell, ax1,ay1,ax2,ay2);
  float aarea = (ax2-ax1)*(ay2-ay1);

  u64 pcbits = 0, ncbits = 0;              // wave-uniform (SGPR) accumulation
  u64 bk = 0;                              // per-lane: best (iou,~i) for gt=lane

  for (int k = 0; k < 64; ++k){
    float bx1 = rdlane(ax1,k), by1 = rdlane(ay1,k);
    float bx2 = rdlane(ax2,k), by2 = rdlane(ay2,k);
    float ba  = rdlane(aarea,k);
    float ix1 = fmaxf(bx1,gx1), iy1 = fmaxf(by1,gy1);
    float ix2 = fminf(bx2,gx2), iy2 = fminf(by2,gy2);
    float iw = fmaxf(ix2-ix1, 0.0f), ih = fmaxf(iy2-iy1, 0.0f);
    float inter = iw*ih;
    if (__ballot(inter != 0.0f) == 0ull){  // uniform fast path: iou==0 for all gts
      ncbits |= 1ull << k;                 // matched_iou==0 < 0.3; not >0.7; no bk
      continue;
    }
    float den = ba + garea;                // exact reference op order, no FMA
    den = den - inter;
    den = den + 1e-7f;
    float iou = inter / den;
    u64 pcb = __ballot(iou > 0.7f);        // any gt > FG_T
    u64 ncb = __ballot(iou >= 0.3f);       // none >= BG_T  <=>  max < BG_T
    if (pcb) pcbits |= 1ull << k;
    if (!ncb) ncbits |= 1ull << k;
    u32 ib = __float_as_uint(iou);         // iou >= 0: bits order-isomorphic
    u64 key = ((u64)ib << 32) | (u64)(0xFFFFFFFFu - (u32)(cbase + k));
    if (ib && key > bk) bk = key;          // per-gt running argmax (smaller i wins ties)
  }

  // ---- phase B: lane = anchor; threefry + rank values + hist ----
  int i = cbase + lane;
  bool pc = (pcbits >> lane) & 1ull;
  bool nc = (ncbits >> lane) & 1ull;
  u32 rp = 0, rn = 0;
  if (pcbits){                             // wave-uniform skip (pos is rare)
    u32 a0,a1;
    tf2x32(keys.k[b][0], keys.k[b][1], 0u, (u32)i, a0,a1);
    u32 ph = (a0^a1) >> 9;
    rp = pc ? ph + 1u : 0u;
    if (pc) atomicAdd(&hist[((b*2+0)<<12) + (ph>>11)], 1u);
  }
  if (ncbits){
    u32 c0,c1;
    tf2x32(keys.k[b][2], keys.k[b][3], 0u, (u32)i, c0,c1);
    u32 nh = (c0^c1) >> 9;
    rn = nc ? nh + 1u : 0u;
    if (nc) atomicAdd(&hist[((b*2+1)<<12) + (nh>>11)], 1u);
  }
  rpv[b*NN_+i] = rp;
  rnv[b*NN_+i] = rn;
  if (lane == 0){
    u32 np = (u32)__popcll(pcbits), nn = (u32)__popcll(ncbits);
    if (np) atomicAdd(&counts[b*2+0], np);
    if (nn) atomicAdd(&counts[b*2+1], nn);
  }

  // ---- per-block combine of per-gt bests, then filtered global atomicMax ----
  __shared__ u64 wl[128];
  wl[wid*64 + lane] = bk;
  __syncthreads();
  if (tid < 64){
    u64 m0 = wl[tid], m1 = wl[64+tid];
    u64 m = m0 > m1 ? m0 : m1;
    if ((u32)(m >> 32) != 0u) atomicMax(&bestkey[b*MM_ + tid], m);
  }
}

// ---------------- K2: forced-anchor fixup (dedup via atomicExch) ----------------
__global__ __launch_bounds__(64) void k_fix(const u64* __restrict__ bestkey, Keys keys,
                                            u32* __restrict__ rpv,
                                            u32* __restrict__ counts, u32* __restrict__ hist){
  int b = blockIdx.x, j = threadIdx.x;
  u64 key = bestkey[b*MM_ + j];
  bool add = false;
  if ((u32)(key >> 32) != 0u){    // best_iou > 0
    u32 ist = 0xFFFFFFFFu - (u32)key;
    u32 a0,a1;
    tf2x32(keys.k[b][0], keys.k[b][1], 0u, ist, a0,a1);
    u32 ph = (a0^a1) >> 9;
    u32 old = atomicExch(&rpv[b*NN_ + ist], ph + 1u);   // same value regardless of writer
    if (old == 0u){
      add = true;
      atomicAdd(&hist[((b*2+0)<<12) + (ph>>11)], 1u);
    }
  }
  u64 bal = __ballot(add);
  if (j == 0 && bal) atomicAdd(&counts[b*2+0], (u32)__popcll(bal));
}

// ---------------- K3: threshold bin + collect + exact (vstar,cut) ----------------
__global__ __launch_bounds__(256) void k_sel(const u32* __restrict__ rpv,
                                             const u32* __restrict__ rnv,
                                             const u32* __restrict__ counts,
                                             const u32* __restrict__ hist,
                                             u32* __restrict__ selp){
  int cls = blockIdx.x, b = blockIdx.y, tid = threadIdx.x;
  int id = b*2 + cls;
  u32 posc = counts[b*2+0], negc = counts[b*2+1];
  u32 npos = min(posc, POS_CAP_);
  u32 K   = cls ? (BATCH_ - npos) : npos;
  u32 cnt = cls ? negc : posc;
  if (cnt <= K){
    if (tid == 0){ selp[id*2+0] = 0u; selp[id*2+1] = 0xFFFFFFFFu; }
    return;
  }
  const u32* H = hist + (id << 12);
  __shared__ u32 ts[256], ss[256];
  __shared__ u32 bc[2];
  u32 s = 0;
  #pragma unroll
  for (int q = 0; q < 16; ++q) s += H[tid*16 + q];
  ts[tid] = s; ss[tid] = s;
  __syncthreads();
  for (int off = 1; off < 256; off <<= 1){
    u32 vv = (tid + off < 256) ? ss[tid + off] : 0u;
    __syncthreads();
    ss[tid] += vv;
    __syncthreads();
  }
  u32 excl = (tid < 255) ? ss[tid+1] : 0u;
  if (excl < K && excl + ts[tid] >= K){
    u32 acc = excl;
    for (int q = 15; q >= 0; --q){
      u32 h = H[tid*16 + q];
      if (acc + h >= K){ bc[0] = (u32)(tid*16 + q); bc[1] = K - acc; break; }
      acc += h;
    }
  }
  __syncthreads();
  u32 B = bc[0], Kp = bc[1];
  const u32* v = (cls ? rnv : rpv) + (size_t)b*NN_;
  __shared__ u64 L[512];
  __shared__ u32 lc;
  if (tid == 0) lc = 0;
  __syncthreads();
  for (int i2 = tid; i2 < NN_; i2 += 256){
    u32 xv = v[i2];
    if (xv && ((xv - 1u) >> 11) == B){
      u32 p = atomicAdd(&lc, 1u);
      if (p < 512u) L[p] = ((u64)xv << 32) | (u32)i2;
    }
  }
  __syncthreads();
  u32 n = min(lc, 512u);
  for (u32 e = tid; e < n; e += 256){
    u64 me = L[e]; u32 mv = (u32)(me >> 32), mi = (u32)me;
    u32 r = 0;
    for (u32 t2 = 0; t2 < n; ++t2){
      u64 o = L[t2]; u32 ov = (u32)(o >> 32), oi = (u32)o;
      r += (ov > mv) || (ov == mv && oi < mi);
    }
    if (r == Kp - 1u){ selp[id*2+0] = mv; selp[id*2+1] = mi; }
  }
}

// ---------------- K4: final cls + offsets (argmax recomputed for selpos only) ----------------
__global__ __launch_bounds__(256) void k_out(const float* __restrict__ x,
                                             const u32* __restrict__ rpv,
                                             const u32* __restrict__ rnv,
                                             const u32* __restrict__ selp,
                                             float* __restrict__ out){
  #pragma clang fp contract(off)
  int b = blockIdx.y, tid = threadIdx.x;
  __shared__ float g[MM_][4];
  g[tid>>2][tid&3] = x[b*MM_*XROW_ + (tid>>2)*XROW_ + 21 + (tid&3)];
  __syncthreads();
  int i = blockIdx.x*256 + tid;
  if (i >= NN_) return;

  u32 pth = selp[(b*2+0)*2+0], pcut = selp[(b*2+0)*2+1];
  u32 nth = selp[(b*2+1)*2+0], ncut = selp[(b*2+1)*2+1];
  u32 pv = rpv[b*NN_+i], nv = rnv[b*NN_+i];
  bool selpos = (pv > 0u) && (pv > pth || (pv == pth && (u32)i <= pcut));
  bool selneg = (nv > 0u) && (nv > nth || (nv == nth && (u32)i <= ncut));
  float cls = selpos ? 1.0f : -1.0f;
  if (selneg) cls = 0.0f;

  float tx = 0.0f, ty = 0.0f, tw = 0.0f, th = 0.0f;
  if (selpos){
    int a = i % 9, cell = i / 9;
    float ax1,ay1,ax2,ay2;
    anchor_from(a, cell, ax1,ay1,ax2,ay2);
    float area_a = (ax2-ax1)*(ay2-ay1);
    // recompute argmax over gts (first-max semantics) — selpos only (~1% of threads)
    float best = -1.0f; int bj = 0;
    for (int j = 0; j < MM_; ++j){
      float g0=g[j][0], g1=g[j][1], g2=g[j][2], g3=g[j][3];
      float ix1 = fmaxf(ax1,g0), iy1 = fmaxf(ay1,g1);
      float ix2 = fminf(ax2,g2), iy2 = fminf(ay2,g3);
      float iw = fmaxf(ix2-ix1, 0.0f), ih = fmaxf(iy2-iy1, 0.0f);
      float inter = iw*ih;
      float den = area_a + (g2-g0)*(g3-g1);
      den = den - inter;
      den = den + 1e-7f;
      float iou = inter / den;
      if (iou > best){ best = iou; bj = j; }
    }
    float g0=g[bj][0], g1=g[bj][1], g2=g[bj][2], g3=g[bj][3];
    float wgt = g2-g0, hgt = g3-g1;
    float xcg = (g2+g0)*0.5f, ycg = (g3+g1)*0.5f;
    float wr = ax2-ax1, hr = ay2-ay1;
    float xcr = (ax2+ax1)*0.5f, ycr = (ay2+ay1)*0.5f;
    float wrs = (wr > 0.0f) ? wr : 1.0f;
    float hrs = (hr > 0.0f) ? hr : 1.0f;
    tx = (wgt > 0.0f) ? (xcg - xcr)/wrs : 0.0f;
    ty = (hgt > 0.0f) ? (ycg - ycr)/hrs : 0.0f;
    tw = (wgt > 0.0f) ? logf(wgt/wrs) : 0.0f;
    th = (hgt > 0.0f) ? logf(hgt/hrs) : 0.0f;
  }
  float* o = out + (size_t)(b*NN_+i)*5;
  o[0] = cls; o[1] = tx; o[2] = ty; o[3] = tw; o[4] = th;
}

extern "C" void kernel_launch(void* const* d_in, const int* in_sizes, int n_in,
                              void* d_out, int out_size, void* d_ws, size_t ws_size,
                              hipStream_t stream) {
  const float* x = (const float*)d_in[0];
  float* out = (float*)d_out;
  char* ws = (char*)d_ws;

  // ws layout — zero-span [0, 532736) covers counts+bestkey+hist
  u32* counts  = (u32*)(ws + 0);          // 128 B
  u64* bestkey = (u64*)(ws + 256);        // 8 KiB
  u32* hist    = (u32*)(ws + 8448);       // 512 KiB (2*16*4096*4)
  u32* selp    = (u32*)(ws + 532736);     // 256 B (always fully written by k_sel)
  u32* rpv = (u32*)(ws + 532992);         // 1.76 MiB
  u32* rnv = (u32*)(ws + 2376192);        // 1.76 MiB (end ~4.2 MiB)
  (void)ws_size; (void)in_sizes; (void)n_in; (void)out_size;

  // host-side JAX key derivation (partitionable threefry), deterministic
  Keys keys;
  for (int b = 0; b < BB_; ++b){
    u32 r0, r1;
    tf2x32(0u, 42u, 0u, (u32)b, r0, r1);
    tf2x32(r0, r1, 0u, 0u, keys.k[b][0], keys.k[b][1]);
    tf2x32(r0, r1, 0u, 1u, keys.k[b][2], keys.k[b][3]);
  }

  hipMemsetAsync(ws, 0, 532736, stream);
  k_main<<<dim3(225, BB_), 128, 0, stream>>>(x, keys, bestkey, rpv, rnv, counts, hist);
  k_fix <<<dim3(BB_), 64, 0, stream>>>(bestkey, keys, rpv, counts, hist);
  k_sel <<<dim3(2, BB_), 256, 0, stream>>>(rpv, rnv, counts, hist, selp);
  k_out <<<dim3(113, BB_), 256, 0, stream>>>(x, rpv, rnv, selp, out);
}

// Round 7
// 156.386 us; speedup vs baseline: 1.0118x; 1.0118x over previous
//
#include <hip/hip_runtime.h>
#include <stdint.h>
#include <math.h>

typedef unsigned int u32;
typedef unsigned long long u64;

#define NN_ 28800
#define MM_ 64
#define BB_ 16
#define XROW_ 25
#define POS_CAP_ 128u
#define BATCH_ 256u

struct Keys { u32 k[BB_][4]; };

// ---------------- threefry2x32 (JAX-exact), host+device ----------------
__host__ __device__ __forceinline__ u32 rotl32(u32 v, u32 r){ return (v<<r)|(v>>(32u-r)); }

__host__ __device__ __forceinline__ void tf2x32(u32 k0, u32 k1, u32 x0, u32 x1, u32& y0, u32& y1){
  u32 ks2 = k0 ^ k1 ^ 0x1BD11BDAu;
  x0 += k0; x1 += k1;
#define TFR(r) { x0 += x1; x1 = rotl32(x1,(r)); x1 ^= x0; }
  TFR(13) TFR(15) TFR(26) TFR(6)   x0 += k1;  x1 += ks2 + 1u;
  TFR(17) TFR(29) TFR(16) TFR(24)  x0 += ks2; x1 += k0  + 2u;
  TFR(13) TFR(15) TFR(26) TFR(6)   x0 += k0;  x1 += k1  + 3u;
  TFR(17) TFR(29) TFR(16) TFR(24)  x0 += k1;  x1 += ks2 + 4u;
  TFR(13) TFR(15) TFR(26) TFR(6)   x0 += ks2; x1 += k0  + 5u;
#undef TFR
  y0 = x0; y1 = x1;
}

// ---------------- anchors: pure-float, bit-exact vs numpy ----------------
__device__ __forceinline__ void anchor_from(int a, int cell,
                                            float& ox1, float& oy1, float& ox2, float& oy2){
  #pragma clang fp contract(off)
  int w = cell & 63;
  int h = cell >> 6;
  int p = (a >= 6) ? 2 : ((a >= 3) ? 1 : 0);
  int q = a - p*3;
  float sf = (p==0) ? 128.0f : ((p==1) ? 256.0f : 512.0f);
  const float SQH = 0.70710678118654752440f;
  const float SQ2 = 1.41421356237309514547f;
  float cw = (q==0) ? SQH : ((q==1) ? 1.0f : SQ2);
  float ch = (q==0) ? SQ2 : ((q==1) ? 1.0f : SQH);
  float hx = (sf*cw) * 0.5f;
  float hy = (sf*ch) * 0.5f;
  float cx = ((float)w + 0.5f) * 16.0f;
  float cy = ((float)h + 0.5f) * 16.0f;
  float X1 = (cx - hx) / 1024.0f;
  float Y1 = (cy - hy) / 800.0f;
  float X2 = (cx + hx) / 1024.0f;
  float Y2 = (cy + hy) / 800.0f;
  bool valid = (X1 > 0.0f) && (Y1 > 0.0f) && (X2 < 1.0f) && (Y2 < 1.0f);
  ox1 = valid ? X1 : 0.0f;
  oy1 = valid ? Y1 : 0.0f;
  ox2 = valid ? X2 : 0.0f;
  oy2 = valid ? Y2 : 0.0f;
}

__device__ __forceinline__ float rdlane(float v, int k){
  return __int_as_float(__builtin_amdgcn_readlane(__float_as_int(v), k));
}

// ---------------- K1: transposed (lane = gt); scalar validity skip; no hist ----------------
__global__ __launch_bounds__(128, 6) void k_main(const float* __restrict__ x, Keys keys,
                                                 u64* __restrict__ bestkey,
                                                 u32* __restrict__ rpv, u32* __restrict__ rnv,
                                                 u32* __restrict__ counts){
  #pragma clang fp contract(off)
  int tid = threadIdx.x;          // 0..127 (2 waves)
  int lane = tid & 63;
  int wid = tid >> 6;
  int b = blockIdx.y;
  int cbase = (blockIdx.x*2 + wid)*64;     // this wave's 64-anchor chunk

  // lane j holds gt j in registers
  const float* gp = x + (b*MM_ + lane)*XROW_ + 21;
  float gx1 = gp[0], gy1 = gp[1], gx2 = gp[2], gy2 = gp[3];
  float garea = (gx2-gx1)*(gy2-gy1);       // exact reference op order

  // lane k holds anchor (cbase+k)'s box
  int ia = cbase + lane;
  int a = ia % 9, cell = ia / 9;
  float ax1,ay1,ax2,ay2;
  anchor_from(a, cell, ax1,ay1,ax2,ay2);
  float aarea = (ax2-ax1)*(ay2-ay1);

  u64 valid_mask = __ballot(ax2 > 0.0f);   // anchor (cbase+k) validity, wave-uniform
  u64 pcbits = 0, ncbits = 0;              // wave-uniform (SGPR) accumulation
  u64 bk = 0;                              // per-lane: best (iou,~i) for gt=lane

  for (int k = 0; k < 64; ++k){
    if (!((valid_mask >> k) & 1ull)){      // invalid anchor: iou==0 vs all gts
      ncbits |= 1ull << k;                 // matched_iou==0 < 0.3; not >0.7; no bk
      continue;
    }
    float bx1 = rdlane(ax1,k), by1 = rdlane(ay1,k);
    float bx2 = rdlane(ax2,k), by2 = rdlane(ay2,k);
    float ba  = rdlane(aarea,k);
    float ix1 = fmaxf(bx1,gx1), iy1 = fmaxf(by1,gy1);
    float ix2 = fminf(bx2,gx2), iy2 = fminf(by2,gy2);
    float iw = fmaxf(ix2-ix1, 0.0f), ih = fmaxf(iy2-iy1, 0.0f);
    float inter = iw*ih;
    float den = ba + garea;                // exact reference op order, no FMA
    den = den - inter;
    den = den + 1e-7f;
    float iou = inter / den;
    u64 pcb = __ballot(iou > 0.7f);        // any gt > FG_T
    u64 ncb = __ballot(iou >= 0.3f);       // none >= BG_T  <=>  max < BG_T
    if (pcb) pcbits |= 1ull << k;
    if (!ncb) ncbits |= 1ull << k;
    u32 ib = __float_as_uint(iou);         // iou >= 0: bits order-isomorphic
    u64 key = ((u64)ib << 32) | (u64)(0xFFFFFFFFu - (u32)(cbase + k));
    if (ib && key > bk) bk = key;          // per-gt running argmax (smaller i wins ties)
  }

  // ---- phase B: lane = anchor; threefry + rank values ----
  int i = cbase + lane;
  bool pc = (pcbits >> lane) & 1ull;
  bool nc = (ncbits >> lane) & 1ull;
  u32 rp = 0, rn = 0;
  if (pcbits){                             // wave-uniform skip (pos is rare)
    u32 a0,a1;
    tf2x32(keys.k[b][0], keys.k[b][1], 0u, (u32)i, a0,a1);
    rp = pc ? ((a0^a1) >> 9) + 1u : 0u;
  }
  if (ncbits){
    u32 c0,c1;
    tf2x32(keys.k[b][2], keys.k[b][3], 0u, (u32)i, c0,c1);
    rn = nc ? ((c0^c1) >> 9) + 1u : 0u;
  }
  rpv[b*NN_+i] = rp;
  rnv[b*NN_+i] = rn;
  if (lane == 0){
    u32 np = (u32)__popcll(pcbits), nn = (u32)__popcll(ncbits);
    if (np) atomicAdd(&counts[b*2+0], np);
    if (nn) atomicAdd(&counts[b*2+1], nn);
  }

  // ---- per-block combine of per-gt bests, then filtered global atomicMax ----
  __shared__ u64 wl[128];
  wl[wid*64 + lane] = bk;
  __syncthreads();
  if (tid < 64){
    u64 m0 = wl[tid], m1 = wl[64+tid];
    u64 m = m0 > m1 ? m0 : m1;
    if ((u32)(m >> 32) != 0u) atomicMax(&bestkey[b*MM_ + tid], m);
  }
}

// ---------------- K2: forced-anchor fixup (dedup via atomicExch) ----------------
__global__ __launch_bounds__(64) void k_fix(const u64* __restrict__ bestkey, Keys keys,
                                            u32* __restrict__ rpv,
                                            u32* __restrict__ counts){
  int b = blockIdx.x, j = threadIdx.x;
  u64 key = bestkey[b*MM_ + j];
  bool add = false;
  if ((u32)(key >> 32) != 0u){    // best_iou > 0
    u32 ist = 0xFFFFFFFFu - (u32)key;
    u32 a0,a1;
    tf2x32(keys.k[b][0], keys.k[b][1], 0u, ist, a0,a1);
    u32 ph = (a0^a1) >> 9;
    u32 old = atomicExch(&rpv[b*NN_ + ist], ph + 1u);   // same value regardless of writer
    if (old == 0u) add = true;
  }
  u64 bal = __ballot(add);
  if (j == 0 && bal) atomicAdd(&counts[b*2+0], (u32)__popcll(bal));
}

// ---------------- K3: LDS hist from scan + threshold bin + collect + exact (vstar,cut) ----------------
__global__ __launch_bounds__(256) void k_sel(const u32* __restrict__ rpv,
                                             const u32* __restrict__ rnv,
                                             const u32* __restrict__ counts,
                                             u32* __restrict__ selp){
  int cls = blockIdx.x, b = blockIdx.y, tid = threadIdx.x;
  int id = b*2 + cls;
  u32 posc = counts[b*2+0], negc = counts[b*2+1];
  u32 npos = min(posc, POS_CAP_);
  u32 K   = cls ? (BATCH_ - npos) : npos;
  u32 cnt = cls ? negc : posc;
  if (cnt <= K){
    if (tid == 0){ selp[id*2+0] = 0u; selp[id*2+1] = 0xFFFFFFFFu; }
    return;
  }
  const u32* v = (cls ? rnv : rpv) + (size_t)b*NN_;
  __shared__ u32 hist[4096];
  __shared__ u32 ts[256], ss[256];
  __shared__ u32 bc[2];
  __shared__ u64 L[512];
  __shared__ u32 lc;
  #pragma unroll
  for (int h = 0; h < 16; ++h) hist[h*256 + tid] = 0;
  if (tid == 0) lc = 0;
  __syncthreads();
  // pass 1: LDS histogram of high 12 bits of (v-1)
  for (int i2 = tid; i2 < NN_; i2 += 256){
    u32 xv = v[i2];
    if (xv) atomicAdd(&hist[(xv-1u)>>11], 1u);
  }
  __syncthreads();
  u32 s = 0;
  #pragma unroll
  for (int q = 0; q < 16; ++q) s += hist[tid*16 + q];
  ts[tid] = s; ss[tid] = s;
  __syncthreads();
  for (int off = 1; off < 256; off <<= 1){
    u32 vv = (tid + off < 256) ? ss[tid + off] : 0u;
    __syncthreads();
    ss[tid] += vv;
    __syncthreads();
  }
  u32 excl = (tid < 255) ? ss[tid+1] : 0u;
  if (excl < K && excl + ts[tid] >= K){
    u32 acc = excl;
    for (int q = 15; q >= 0; --q){
      u32 h = hist[tid*16 + q];
      if (acc + h >= K){ bc[0] = (u32)(tid*16 + q); bc[1] = K - acc; break; }
      acc += h;
    }
  }
  __syncthreads();
  u32 B = bc[0], Kp = bc[1];
  // pass 2: collect bin-B members
  for (int i2 = tid; i2 < NN_; i2 += 256){
    u32 xv = v[i2];
    if (xv && ((xv - 1u) >> 11) == B){
      u32 p = atomicAdd(&lc, 1u);
      if (p < 512u) L[p] = ((u64)xv << 32) | (u32)i2;
    }
  }
  __syncthreads();
  u32 n = min(lc, 512u);
  for (u32 e = tid; e < n; e += 256){
    u64 me = L[e]; u32 mv = (u32)(me >> 32), mi = (u32)me;
    u32 r = 0;
    for (u32 t2 = 0; t2 < n; ++t2){
      u64 o = L[t2]; u32 ov = (u32)(o >> 32), oi = (u32)o;
      r += (ov > mv) || (ov == mv && oi < mi);
    }
    if (r == Kp - 1u){ selp[id*2+0] = mv; selp[id*2+1] = mi; }
  }
}

// ---------------- K4: final cls + offsets (argmax recomputed for selpos only) ----------------
__global__ __launch_bounds__(256) void k_out(const float* __restrict__ x,
                                             const u32* __restrict__ rpv,
                                             const u32* __restrict__ rnv,
                                             const u32* __restrict__ selp,
                                             float* __restrict__ out){
  #pragma clang fp contract(off)
  int b = blockIdx.y, tid = threadIdx.x;
  __shared__ float g[MM_][4];
  g[tid>>2][tid&3] = x[b*MM_*XROW_ + (tid>>2)*XROW_ + 21 + (tid&3)];
  __syncthreads();
  int i = blockIdx.x*256 + tid;
  if (i >= NN_) return;

  u32 pth = selp[(b*2+0)*2+0], pcut = selp[(b*2+0)*2+1];
  u32 nth = selp[(b*2+1)*2+0], ncut = selp[(b*2+1)*2+1];
  u32 pv = rpv[b*NN_+i], nv = rnv[b*NN_+i];
  bool selpos = (pv > 0u) && (pv > pth || (pv == pth && (u32)i <= pcut));
  bool selneg = (nv > 0u) && (nv > nth || (nv == nth && (u32)i <= ncut));
  float cls = selpos ? 1.0f : -1.0f;
  if (selneg) cls = 0.0f;

  float tx = 0.0f, ty = 0.0f, tw = 0.0f, th = 0.0f;
  if (selpos){
    int a = i % 9, cell = i / 9;
    float ax1,ay1,ax2,ay2;
    anchor_from(a, cell, ax1,ay1,ax2,ay2);
    float area_a = (ax2-ax1)*(ay2-ay1);
    float best = -1.0f; int bj = 0;
    for (int j = 0; j < MM_; ++j){
      float g0=g[j][0], g1=g[j][1], g2=g[j][2], g3=g[j][3];
      float ix1 = fmaxf(ax1,g0), iy1 = fmaxf(ay1,g1);
      float ix2 = fminf(ax2,g2), iy2 = fminf(ay2,g3);
      float iw = fmaxf(ix2-ix1, 0.0f), ih = fmaxf(iy2-iy1, 0.0f);
      float inter = iw*ih;
      float den = area_a + (g2-g0)*(g3-g1);
      den = den - inter;
      den = den + 1e-7f;
      float iou = inter / den;
      if (iou > best){ best = iou; bj = j; }
    }
    float g0=g[bj][0], g1=g[bj][1], g2=g[bj][2], g3=g[bj][3];
    float wgt = g2-g0, hgt = g3-g1;
    float xcg = (g2+g0)*0.5f, ycg = (g3+g1)*0.5f;
    float wr = ax2-ax1, hr = ay2-ay1;
    float xcr = (ax2+ax1)*0.5f, ycr = (ay2+ay1)*0.5f;
    float wrs = (wr > 0.0f) ? wr : 1.0f;
    float hrs = (hr > 0.0f) ? hr : 1.0f;
    tx = (wgt > 0.0f) ? (xcg - xcr)/wrs : 0.0f;
    ty = (hgt > 0.0f) ? (ycg - ycr)/hrs : 0.0f;
    tw = (wgt > 0.0f) ? logf(wgt/wrs) : 0.0f;
    th = (hgt > 0.0f) ? logf(hgt/hrs) : 0.0f;
  }
  float* o = out + (size_t)(b*NN_+i)*5;
  o[0] = cls; o[1] = tx; o[2] = ty; o[3] = tw; o[4] = th;
}

extern "C" void kernel_launch(void* const* d_in, const int* in_sizes, int n_in,
                              void* d_out, int out_size, void* d_ws, size_t ws_size,
                              hipStream_t stream) {
  const float* x = (const float*)d_in[0];
  float* out = (float*)d_out;
  char* ws = (char*)d_ws;

  // ws layout — zero-span [0, 8448) covers counts + bestkey
  u32* counts  = (u32*)(ws + 0);          // 128 B
  u64* bestkey = (u64*)(ws + 256);        // 8 KiB
  u32* selp    = (u32*)(ws + 8448);       // 256 B (always fully written by k_sel)
  u32* rpv = (u32*)(ws + 8704);           // 1.76 MiB
  u32* rnv = (u32*)(ws + 1851904);        // 1.76 MiB (end ~3.7 MiB)
  (void)ws_size; (void)in_sizes; (void)n_in; (void)out_size;

  // host-side JAX key derivation (partitionable threefry), deterministic
  Keys keys;
  for (int b = 0; b < BB_; ++b){
    u32 r0, r1;
    tf2x32(0u, 42u, 0u, (u32)b, r0, r1);
    tf2x32(r0, r1, 0u, 0u, keys.k[b][0], keys.k[b][1]);
    tf2x32(r0, r1, 0u, 1u, keys.k[b][2], keys.k[b][3]);
  }

  hipMemsetAsync(ws, 0, 8448, stream);
  k_main<<<dim3(225, BB_), 128, 0, stream>>>(x, keys, bestkey, rpv, rnv, counts);
  k_fix <<<dim3(BB_), 64, 0, stream>>>(bestkey, keys, rpv, counts);
  k_sel <<<dim3(2, BB_), 256, 0, stream>>>(rpv, rnv, counts, selp);
  k_out <<<dim3(113, BB_), 256, 0, stream>>>(x, rpv, rnv, selp, out);
}

// Round 8
// 92.661 us; speedup vs baseline: 1.7076x; 1.6877x over previous
//
#include <hip/hip_runtime.h>
#include <stdint.h>
#include <math.h>

typedef unsigned int u32;
typedef unsigned long long u64;

#define NN_ 28800
#define MM_ 64
#define BB_ 16
#define XROW_ 25
#define POS_CAP_ 128u
#define BATCH_ 256u
#define NBLK_ 225                 // k_main blocks per image (128 anchors each)

struct Keys { u32 k[BB_][4]; };

// ---------------- threefry2x32 (JAX-exact), host+device ----------------
__host__ __device__ __forceinline__ u32 rotl32(u32 v, u32 r){ return (v<<r)|(v>>(32u-r)); }

__host__ __device__ __forceinline__ void tf2x32(u32 k0, u32 k1, u32 x0, u32 x1, u32& y0, u32& y1){
  u32 ks2 = k0 ^ k1 ^ 0x1BD11BDAu;
  x0 += k0; x1 += k1;
#define TFR(r) { x0 += x1; x1 = rotl32(x1,(r)); x1 ^= x0; }
  TFR(13) TFR(15) TFR(26) TFR(6)   x0 += k1;  x1 += ks2 + 1u;
  TFR(17) TFR(29) TFR(16) TFR(24)  x0 += ks2; x1 += k0  + 2u;
  TFR(13) TFR(15) TFR(26) TFR(6)   x0 += k0;  x1 += k1  + 3u;
  TFR(17) TFR(29) TFR(16) TFR(24)  x0 += k1;  x1 += ks2 + 4u;
  TFR(13) TFR(15) TFR(26) TFR(6)   x0 += ks2; x1 += k0  + 5u;
#undef TFR
  y0 = x0; y1 = x1;
}

// ---------------- anchors: pure-float, bit-exact vs numpy ----------------
__device__ __forceinline__ void anchor_from(int a, int cell,
                                            float& ox1, float& oy1, float& ox2, float& oy2){
  #pragma clang fp contract(off)
  int w = cell & 63;
  int h = cell >> 6;
  int p = (a >= 6) ? 2 : ((a >= 3) ? 1 : 0);
  int q = a - p*3;
  float sf = (p==0) ? 128.0f : ((p==1) ? 256.0f : 512.0f);
  const float SQH = 0.70710678118654752440f;
  const float SQ2 = 1.41421356237309514547f;
  float cw = (q==0) ? SQH : ((q==1) ? 1.0f : SQ2);
  float ch = (q==0) ? SQ2 : ((q==1) ? 1.0f : SQH);
  float hx = (sf*cw) * 0.5f;
  float hy = (sf*ch) * 0.5f;
  float cx = ((float)w + 0.5f) * 16.0f;
  float cy = ((float)h + 0.5f) * 16.0f;
  float X1 = (cx - hx) / 1024.0f;
  float Y1 = (cy - hy) / 800.0f;
  float X2 = (cx + hx) / 1024.0f;
  float Y2 = (cy + hy) / 800.0f;
  bool valid = (X1 > 0.0f) && (Y1 > 0.0f) && (X2 < 1.0f) && (Y2 < 1.0f);
  ox1 = valid ? X1 : 0.0f;
  oy1 = valid ? Y1 : 0.0f;
  ox2 = valid ? X2 : 0.0f;
  oy2 = valid ? Y2 : 0.0f;
}

__device__ __forceinline__ float rdlane(float v, int k){
  return __int_as_float(__builtin_amdgcn_readlane(__float_as_int(v), k));
}

__device__ __forceinline__ float iou_of(float bx1,float by1,float bx2,float by2,float ba,
                                        float gx1,float gy1,float gx2,float gy2,float garea){
  #pragma clang fp contract(off)
  float ix1 = fmaxf(bx1,gx1), iy1 = fmaxf(by1,gy1);
  float ix2 = fminf(bx2,gx2), iy2 = fminf(by2,gy2);
  float iw = fmaxf(ix2-ix1, 0.0f), ih = fmaxf(iy2-iy1, 0.0f);
  float inter = iw*ih;
  float den = ba + garea;        // exact reference op order, no FMA
  den = den - inter;
  den = den + 1e-7f;
  return inter / den;
}

// ---------------- K1: transposed (lane = gt); valid-bit iteration ×2; NO atomics ----------------
__global__ __launch_bounds__(128, 6) void k_main(const float* __restrict__ x, Keys keys,
                                                 u64* __restrict__ bestpart,
                                                 u32* __restrict__ cnts_part,
                                                 u32* __restrict__ rpv, u32* __restrict__ rnv){
  #pragma clang fp contract(off)
  int tid = threadIdx.x;          // 0..127 (2 waves)
  int lane = tid & 63;
  int wid = tid >> 6;
  int bx = blockIdx.x;
  int b = blockIdx.y;
  int cbase = (bx*2 + wid)*64;    // this wave's 64-anchor chunk

  // lane j holds gt j in registers
  const float* gp = x + (b*MM_ + lane)*XROW_ + 21;
  float gx1 = gp[0], gy1 = gp[1], gx2 = gp[2], gy2 = gp[3];
  float garea = (gx2-gx1)*(gy2-gy1);

  // lane k holds anchor (cbase+k)'s box
  int ia = cbase + lane;
  int a = ia % 9, cell = ia / 9;
  float ax1,ay1,ax2,ay2;
  anchor_from(a, cell, ax1,ay1,ax2,ay2);
  float aarea = (ax2-ax1)*(ay2-ay1);

  u64 valid_mask = __ballot(ax2 > 0.0f);
  u64 pcbits = 0;
  u64 ncbits = ~valid_mask;       // invalid anchors: miou==0 -> neg cand, not pos
  u64 bk = 0;                     // per-lane: best (iou,~i) for gt=lane

  u64 vm = valid_mask;
  while (vm){
    int k1 = __ffsll((unsigned long long)vm) - 1; vm &= vm - 1ull;
    int k2 = vm ? __ffsll((unsigned long long)vm) - 1 : k1; vm &= vm - 1ull;  // safe on 0
    // two independent chains -> ILP
    float c1x1=rdlane(ax1,k1), c1y1=rdlane(ay1,k1), c1x2=rdlane(ax2,k1), c1y2=rdlane(ay2,k1), c1a=rdlane(aarea,k1);
    float c2x1=rdlane(ax1,k2), c2y1=rdlane(ay1,k2), c2x2=rdlane(ax2,k2), c2y2=rdlane(ay2,k2), c2a=rdlane(aarea,k2);
    float i1 = iou_of(c1x1,c1y1,c1x2,c1y2,c1a, gx1,gy1,gx2,gy2,garea);
    float i2 = iou_of(c2x1,c2y1,c2x2,c2y2,c2a, gx1,gy1,gx2,gy2,garea);
    u64 p1 = __ballot(i1 > 0.7f);
    u64 n1 = __ballot(i1 >= 0.3f);
    u64 p2 = __ballot(i2 > 0.7f);
    u64 n2 = __ballot(i2 >= 0.3f);
    if (p1)  pcbits |= 1ull << k1;
    if (!n1) ncbits |= 1ull << k1;
    if (p2)  pcbits |= 1ull << k2;
    if (!n2) ncbits |= 1ull << k2;
    u32 q1 = __float_as_uint(i1);
    u32 q2 = __float_as_uint(i2);
    u64 key1 = ((u64)q1 << 32) | (u64)(0xFFFFFFFFu - (u32)(cbase + k1));
    u64 key2 = ((u64)q2 << 32) | (u64)(0xFFFFFFFFu - (u32)(cbase + k2));
    if (q1 && key1 > bk) bk = key1;    // k1 < k2: smaller i wins ties via ~i encoding
    if (q2 && key2 > bk) bk = key2;
  }

  // ---- phase B: lane = anchor; threefry + rank values ----
  int i = cbase + lane;
  bool pc = (pcbits >> lane) & 1ull;
  bool nc = (ncbits >> lane) & 1ull;
  u32 rp = 0, rn = 0;
  if (pcbits){                    // wave-uniform skip (pos is rare)
    u32 a0,a1;
    tf2x32(keys.k[b][0], keys.k[b][1], 0u, (u32)i, a0,a1);
    rp = pc ? ((a0^a1) >> 9) + 1u : 0u;
  }
  if (ncbits){
    u32 c0,c1;
    tf2x32(keys.k[b][2], keys.k[b][3], 0u, (u32)i, c0,c1);
    rn = nc ? ((c0^c1) >> 9) + 1u : 0u;
  }
  rpv[b*NN_+i] = rp;
  rnv[b*NN_+i] = rn;

  // ---- per-block combine + plain coalesced stores (no atomics, no pre-zero) ----
  __shared__ u64 wl[128];
  __shared__ u32 scnt[4];
  wl[wid*64 + lane] = bk;
  if (lane == 0){
    scnt[wid*2+0] = (u32)__popcll(pcbits);
    scnt[wid*2+1] = (u32)__popcll(ncbits);
  }
  __syncthreads();
  if (tid < 64){
    u64 m0 = wl[tid], m1 = wl[64+tid];
    bestpart[((size_t)(b*NBLK_ + bx))*64 + tid] = m0 > m1 ? m0 : m1;
  }
  if (tid == 0){
    cnts_part[(b*NBLK_ + bx)*2 + 0] = scnt[0] + scnt[2];
    cnts_part[(b*NBLK_ + bx)*2 + 1] = scnt[1] + scnt[3];
  }
}

// ---------------- K2: reduce bestpart + counts; forced-anchor fixup ----------------
__global__ __launch_bounds__(64) void k_fix(const u64* __restrict__ bestpart,
                                            const u32* __restrict__ cnts_part,
                                            Keys keys,
                                            u32* __restrict__ rpv,
                                            u32* __restrict__ counts){
  int b = blockIdx.x, lane = threadIdx.x;
  // per-gt max over 225 block-parts (coalesced: 64 lanes read 64 consecutive u64)
  u64 m = 0;
  for (int blk = 0; blk < NBLK_; ++blk){
    u64 v = bestpart[((size_t)(b*NBLK_ + blk))*64 + lane];
    if (v > m) m = v;
  }
  // candidate count sums
  u32 cp = 0, cn = 0;
  for (int t = lane; t < NBLK_; t += 64){
    cp += cnts_part[(b*NBLK_ + t)*2 + 0];
    cn += cnts_part[(b*NBLK_ + t)*2 + 1];
  }
  #pragma unroll
  for (int off = 32; off >= 1; off >>= 1){
    cp += (u32)__shfl_xor((int)cp, off, 64);
    cn += (u32)__shfl_xor((int)cn, off, 64);
  }
  // forced fixup (dedup via atomicExch; only this block touches row b)
  bool add = false;
  if ((u32)(m >> 32) != 0u){      // best_iou > 0
    u32 ist = 0xFFFFFFFFu - (u32)m;
    u32 a0,a1;
    tf2x32(keys.k[b][0], keys.k[b][1], 0u, ist, a0,a1);
    u32 ph = (a0^a1) >> 9;
    u32 old = atomicExch(&rpv[b*NN_ + ist], ph + 1u);   // same value regardless of writer
    add = (old == 0u);
  }
  u64 bal = __ballot(add);
  if (lane == 0){
    counts[b*2+0] = cp + (u32)__popcll(bal);
    counts[b*2+1] = cn;
  }
}

// ---------------- K3: LDS hist + threshold bin + collect + exact (vstar,cut) ----------------
__global__ __launch_bounds__(256) void k_sel(const u32* __restrict__ rpv,
                                             const u32* __restrict__ rnv,
                                             const u32* __restrict__ counts,
                                             u32* __restrict__ selp){
  int cls = blockIdx.x, b = blockIdx.y, tid = threadIdx.x;
  int id = b*2 + cls;
  u32 posc = counts[b*2+0], negc = counts[b*2+1];
  u32 npos = min(posc, POS_CAP_);
  u32 K   = cls ? (BATCH_ - npos) : npos;
  u32 cnt = cls ? negc : posc;
  if (cnt <= K){
    if (tid == 0){ selp[id*2+0] = 0u; selp[id*2+1] = 0xFFFFFFFFu; }
    return;
  }
  const u32* v = (cls ? rnv : rpv) + (size_t)b*NN_;
  const uint4* v4 = (const uint4*)v;
  __shared__ u32 hist[4096];
  __shared__ u32 ts[256], ss[256];
  __shared__ u32 bc[2];
  __shared__ u64 L[512];
  __shared__ u32 lc;
  #pragma unroll
  for (int h = 0; h < 16; ++h) hist[h*256 + tid] = 0;
  if (tid == 0) lc = 0;
  __syncthreads();
  // pass 1: LDS histogram of high 12 bits of (v-1), uint4 loads
  for (int i2 = tid; i2 < NN_/4; i2 += 256){
    uint4 q = v4[i2];
    if (q.x) atomicAdd(&hist[(q.x-1u)>>11], 1u);
    if (q.y) atomicAdd(&hist[(q.y-1u)>>11], 1u);
    if (q.z) atomicAdd(&hist[(q.z-1u)>>11], 1u);
    if (q.w) atomicAdd(&hist[(q.w-1u)>>11], 1u);
  }
  __syncthreads();
  u32 s = 0;
  #pragma unroll
  for (int q = 0; q < 16; ++q) s += hist[tid*16 + q];
  ts[tid] = s; ss[tid] = s;
  __syncthreads();
  for (int off = 1; off < 256; off <<= 1){
    u32 vv = (tid + off < 256) ? ss[tid + off] : 0u;
    __syncthreads();
    ss[tid] += vv;
    __syncthreads();
  }
  u32 excl = (tid < 255) ? ss[tid+1] : 0u;
  if (excl < K && excl + ts[tid] >= K){
    u32 acc = excl;
    for (int q = 15; q >= 0; --q){
      u32 h = hist[tid*16 + q];
      if (acc + h >= K){ bc[0] = (u32)(tid*16 + q); bc[1] = K - acc; break; }
      acc += h;
    }
  }
  __syncthreads();
  u32 B = bc[0], Kp = bc[1];
  // pass 2: collect bin-B members
  for (int i2 = tid; i2 < NN_/4; i2 += 256){
    uint4 q = v4[i2];
    #pragma unroll
    for (int c = 0; c < 4; ++c){
      u32 xv = (c==0)?q.x:(c==1)?q.y:(c==2)?q.z:q.w;
      if (xv && ((xv - 1u) >> 11) == B){
        u32 p = atomicAdd(&lc, 1u);
        if (p < 512u) L[p] = ((u64)xv << 32) | (u32)(i2*4 + c);
      }
    }
  }
  __syncthreads();
  u32 n = min(lc, 512u);
  for (u32 e = tid; e < n; e += 256){
    u64 me = L[e]; u32 mv = (u32)(me >> 32), mi = (u32)me;
    u32 r = 0;
    for (u32 t2 = 0; t2 < n; ++t2){
      u64 o = L[t2]; u32 ov = (u32)(o >> 32), oi = (u32)o;
      r += (ov > mv) || (ov == mv && oi < mi);
    }
    if (r == Kp - 1u){ selp[id*2+0] = mv; selp[id*2+1] = mi; }
  }
}

// ---------------- K4: final cls + offsets (argmax recomputed for selpos only) ----------------
__global__ __launch_bounds__(256) void k_out(const float* __restrict__ x,
                                             const u32* __restrict__ rpv,
                                             const u32* __restrict__ rnv,
                                             const u32* __restrict__ selp,
                                             float* __restrict__ out){
  #pragma clang fp contract(off)
  int b = blockIdx.y, tid = threadIdx.x;
  __shared__ float g[MM_][4];
  g[tid>>2][tid&3] = x[b*MM_*XROW_ + (tid>>2)*XROW_ + 21 + (tid&3)];
  __syncthreads();
  int i = blockIdx.x*256 + tid;
  if (i >= NN_) return;

  u32 pth = selp[(b*2+0)*2+0], pcut = selp[(b*2+0)*2+1];
  u32 nth = selp[(b*2+1)*2+0], ncut = selp[(b*2+1)*2+1];
  u32 pv = rpv[b*NN_+i], nv = rnv[b*NN_+i];
  bool selpos = (pv > 0u) && (pv > pth || (pv == pth && (u32)i <= pcut));
  bool selneg = (nv > 0u) && (nv > nth || (nv == nth && (u32)i <= ncut));
  float cls = selpos ? 1.0f : -1.0f;
  if (selneg) cls = 0.0f;

  float tx = 0.0f, ty = 0.0f, tw = 0.0f, th = 0.0f;
  if (selpos){
    int a = i % 9, cell = i / 9;
    float ax1,ay1,ax2,ay2;
    anchor_from(a, cell, ax1,ay1,ax2,ay2);
    float area_a = (ax2-ax1)*(ay2-ay1);
    float best = -1.0f; int bj = 0;
    for (int j = 0; j < MM_; ++j){
      float g0=g[j][0], g1=g[j][1], g2=g[j][2], g3=g[j][3];
      float ix1 = fmaxf(ax1,g0), iy1 = fmaxf(ay1,g1);
      float ix2 = fminf(ax2,g2), iy2 = fminf(ay2,g3);
      float iw = fmaxf(ix2-ix1, 0.0f), ih = fmaxf(iy2-iy1, 0.0f);
      float inter = iw*ih;
      float den = area_a + (g2-g0)*(g3-g1);
      den = den - inter;
      den = den + 1e-7f;
      float iou = inter / den;
      if (iou > best){ best = iou; bj = j; }
    }
    float g0=g[bj][0], g1=g[bj][1], g2=g[bj][2], g3=g[bj][3];
    float wgt = g2-g0, hgt = g3-g1;
    float xcg = (g2+g0)*0.5f, ycg = (g3+g1)*0.5f;
    float wr = ax2-ax1, hr = ay2-ay1;
    float xcr = (ax2+ax1)*0.5f, ycr = (ay2+ay1)*0.5f;
    float wrs = (wr > 0.0f) ? wr : 1.0f;
    float hrs = (hr > 0.0f) ? hr : 1.0f;
    tx = (wgt > 0.0f) ? (xcg - xcr)/wrs : 0.0f;
    ty = (hgt > 0.0f) ? (ycg - ycr)/hrs : 0.0f;
    tw = (wgt > 0.0f) ? logf(wgt/wrs) : 0.0f;
    th = (hgt > 0.0f) ? logf(hgt/hrs) : 0.0f;
  }
  float* o = out + (size_t)(b*NN_+i)*5;
  o[0] = cls; o[1] = tx; o[2] = ty; o[3] = tw; o[4] = th;
}

extern "C" void kernel_launch(void* const* d_in, const int* in_sizes, int n_in,
                              void* d_out, int out_size, void* d_ws, size_t ws_size,
                              hipStream_t stream) {
  const float* x = (const float*)d_in[0];
  float* out = (float*)d_out;
  char* ws = (char*)d_ws;

  // ws layout — NOTHING needs pre-zeroing (all buffers fully overwritten each launch)
  u32* counts    = (u32*)(ws + 0);            // 128 B   (k_fix writes)
  u32* selp      = (u32*)(ws + 256);          // 256 B   (k_sel writes all)
  u64* bestpart  = (u64*)(ws + 512);          // 16*225*64*8 = 1,843,200 B
  u32* cnts_part = (u32*)(ws + 1843712);      // 16*225*2*4 = 28,800 B
  u32* rpv       = (u32*)(ws + 1872640);      // 1,843,200 B
  u32* rnv       = (u32*)(ws + 3715840);      // 1,843,200 B (end ≈ 5.56 MB)
  (void)ws_size; (void)in_sizes; (void)n_in; (void)out_size;

  // host-side JAX key derivation (partitionable threefry), deterministic
  Keys keys;
  for (int b = 0; b < BB_; ++b){
    u32 r0, r1;
    tf2x32(0u, 42u, 0u, (u32)b, r0, r1);
    tf2x32(r0, r1, 0u, 0u, keys.k[b][0], keys.k[b][1]);
    tf2x32(r0, r1, 0u, 1u, keys.k[b][2], keys.k[b][3]);
  }

  k_main<<<dim3(NBLK_, BB_), 128, 0, stream>>>(x, keys, bestpart, cnts_part, rpv, rnv);
  k_fix <<<dim3(BB_), 64, 0, stream>>>(bestpart, cnts_part, keys, rpv, counts);
  k_sel <<<dim3(2, BB_), 256, 0, stream>>>(rpv, rnv, counts, selp);
  k_out <<<dim3(113, BB_), 256, 0, stream>>>(x, rpv, rnv, selp, out);
}

// Round 9
// 75.086 us; speedup vs baseline: 2.1073x; 1.2341x over previous
//
#include <hip/hip_runtime.h>
#include <stdint.h>
#include <math.h>

typedef unsigned int u32;
typedef unsigned long long u64;

#define NN_ 28800
#define MM_ 64
#define BB_ 16
#define XROW_ 25
#define POS_CAP_ 128u
#define BATCH_ 256u
#define NBLK_ 225                 // k_main blocks per image (128 anchors each)

struct Keys { u32 k[BB_][4]; };

// ---------------- threefry2x32 (JAX-exact), host+device ----------------
__host__ __device__ __forceinline__ u32 rotl32(u32 v, u32 r){ return (v<<r)|(v>>(32u-r)); }

__host__ __device__ __forceinline__ void tf2x32(u32 k0, u32 k1, u32 x0, u32 x1, u32& y0, u32& y1){
  u32 ks2 = k0 ^ k1 ^ 0x1BD11BDAu;
  x0 += k0; x1 += k1;
#define TFR(r) { x0 += x1; x1 = rotl32(x1,(r)); x1 ^= x0; }
  TFR(13) TFR(15) TFR(26) TFR(6)   x0 += k1;  x1 += ks2 + 1u;
  TFR(17) TFR(29) TFR(16) TFR(24)  x0 += ks2; x1 += k0  + 2u;
  TFR(13) TFR(15) TFR(26) TFR(6)   x0 += k0;  x1 += k1  + 3u;
  TFR(17) TFR(29) TFR(16) TFR(24)  x0 += k1;  x1 += ks2 + 4u;
  TFR(13) TFR(15) TFR(26) TFR(6)   x0 += ks2; x1 += k0  + 5u;
#undef TFR
  y0 = x0; y1 = x1;
}

// ---------------- anchors: pure-float, bit-exact vs numpy ----------------
__device__ __forceinline__ void anchor_from(int a, int cell,
                                            float& ox1, float& oy1, float& ox2, float& oy2){
  #pragma clang fp contract(off)
  int w = cell & 63;
  int h = cell >> 6;
  int p = (a >= 6) ? 2 : ((a >= 3) ? 1 : 0);
  int q = a - p*3;
  float sf = (p==0) ? 128.0f : ((p==1) ? 256.0f : 512.0f);
  const float SQH = 0.70710678118654752440f;
  const float SQ2 = 1.41421356237309514547f;
  float cw = (q==0) ? SQH : ((q==1) ? 1.0f : SQ2);
  float ch = (q==0) ? SQ2 : ((q==1) ? 1.0f : SQH);
  float hx = (sf*cw) * 0.5f;
  float hy = (sf*ch) * 0.5f;
  float cx = ((float)w + 0.5f) * 16.0f;
  float cy = ((float)h + 0.5f) * 16.0f;
  float X1 = (cx - hx) / 1024.0f;
  float Y1 = (cy - hy) / 800.0f;
  float X2 = (cx + hx) / 1024.0f;
  float Y2 = (cy + hy) / 800.0f;
  bool valid = (X1 > 0.0f) && (Y1 > 0.0f) && (X2 < 1.0f) && (Y2 < 1.0f);
  ox1 = valid ? X1 : 0.0f;
  oy1 = valid ? Y1 : 0.0f;
  ox2 = valid ? X2 : 0.0f;
  oy2 = valid ? Y2 : 0.0f;
}

__device__ __forceinline__ float rdlane(float v, int k){
  return __int_as_float(__builtin_amdgcn_readlane(__float_as_int(v), k));
}

__device__ __forceinline__ float iou_of(float bx1,float by1,float bx2,float by2,float ba,
                                        float gx1,float gy1,float gx2,float gy2,float garea){
  #pragma clang fp contract(off)
  float ix1 = fmaxf(bx1,gx1), iy1 = fmaxf(by1,gy1);
  float ix2 = fminf(bx2,gx2), iy2 = fminf(by2,gy2);
  float iw = fmaxf(ix2-ix1, 0.0f), ih = fmaxf(iy2-iy1, 0.0f);
  float inter = iw*ih;
  float den = ba + garea;        // exact reference op order, no FMA
  den = den - inter;
  den = den + 1e-7f;
  return inter / den;
}

// ---------------- K1: transposed (lane = gt); 4-wide valid-bit iteration; NO atomics ----------------
__global__ __launch_bounds__(128, 6) void k_main(const float* __restrict__ x, Keys keys,
                                                 u64* __restrict__ bestpart,
                                                 u32* __restrict__ cnts_part,
                                                 u32* __restrict__ rpv, u32* __restrict__ rnv){
  #pragma clang fp contract(off)
  int tid = threadIdx.x;          // 0..127 (2 waves)
  int lane = tid & 63;
  int wid = tid >> 6;
  int bx = blockIdx.x;
  int b = blockIdx.y;
  int cbase = (bx*2 + wid)*64;    // this wave's 64-anchor chunk

  // lane j holds gt j in registers
  const float* gp = x + (b*MM_ + lane)*XROW_ + 21;
  float gx1 = gp[0], gy1 = gp[1], gx2 = gp[2], gy2 = gp[3];
  float garea = (gx2-gx1)*(gy2-gy1);

  // lane k holds anchor (cbase+k)'s box
  int ia = cbase + lane;
  int a = ia % 9, cell = ia / 9;
  float ax1,ay1,ax2,ay2;
  anchor_from(a, cell, ax1,ay1,ax2,ay2);
  float aarea = (ax2-ax1)*(ay2-ay1);

  u64 valid_mask = __ballot(ax2 > 0.0f);
  u64 pcbits = 0;
  u64 ncbits = ~valid_mask;       // invalid anchors: miou==0 -> neg cand, not pos
  u64 bk = 0;                     // per-lane: best (iou,~i) for gt=lane

  u64 vm = valid_mask;
  while (vm){
    int k1 = __ffsll((unsigned long long)vm) - 1; vm &= vm - 1ull;
    int k2 = vm ? __ffsll((unsigned long long)vm) - 1 : k1; vm &= vm - 1ull;
    int k3 = vm ? __ffsll((unsigned long long)vm) - 1 : k1; vm &= vm - 1ull;
    int k4 = vm ? __ffsll((unsigned long long)vm) - 1 : k1; vm &= vm - 1ull;
    // four independent chains -> ILP (duplicates are idempotent)
    float c1x1=rdlane(ax1,k1), c1y1=rdlane(ay1,k1), c1x2=rdlane(ax2,k1), c1y2=rdlane(ay2,k1), c1a=rdlane(aarea,k1);
    float c2x1=rdlane(ax1,k2), c2y1=rdlane(ay1,k2), c2x2=rdlane(ax2,k2), c2y2=rdlane(ay2,k2), c2a=rdlane(aarea,k2);
    float c3x1=rdlane(ax1,k3), c3y1=rdlane(ay1,k3), c3x2=rdlane(ax2,k3), c3y2=rdlane(ay2,k3), c3a=rdlane(aarea,k3);
    float c4x1=rdlane(ax1,k4), c4y1=rdlane(ay1,k4), c4x2=rdlane(ax2,k4), c4y2=rdlane(ay2,k4), c4a=rdlane(aarea,k4);
    float i1 = iou_of(c1x1,c1y1,c1x2,c1y2,c1a, gx1,gy1,gx2,gy2,garea);
    float i2 = iou_of(c2x1,c2y1,c2x2,c2y2,c2a, gx1,gy1,gx2,gy2,garea);
    float i3 = iou_of(c3x1,c3y1,c3x2,c3y2,c3a, gx1,gy1,gx2,gy2,garea);
    float i4 = iou_of(c4x1,c4y1,c4x2,c4y2,c4a, gx1,gy1,gx2,gy2,garea);
    u64 p1 = __ballot(i1 > 0.7f), n1 = __ballot(i1 >= 0.3f);
    u64 p2 = __ballot(i2 > 0.7f), n2 = __ballot(i2 >= 0.3f);
    u64 p3 = __ballot(i3 > 0.7f), n3 = __ballot(i3 >= 0.3f);
    u64 p4 = __ballot(i4 > 0.7f), n4 = __ballot(i4 >= 0.3f);
    if (p1)  pcbits |= 1ull << k1;
    if (!n1) ncbits |= 1ull << k1;
    if (p2)  pcbits |= 1ull << k2;
    if (!n2) ncbits |= 1ull << k2;
    if (p3)  pcbits |= 1ull << k3;
    if (!n3) ncbits |= 1ull << k3;
    if (p4)  pcbits |= 1ull << k4;
    if (!n4) ncbits |= 1ull << k4;
    u32 q1 = __float_as_uint(i1), q2 = __float_as_uint(i2);
    u32 q3 = __float_as_uint(i3), q4 = __float_as_uint(i4);
    u64 key1 = ((u64)q1 << 32) | (u64)(0xFFFFFFFFu - (u32)(cbase + k1));
    u64 key2 = ((u64)q2 << 32) | (u64)(0xFFFFFFFFu - (u32)(cbase + k2));
    u64 key3 = ((u64)q3 << 32) | (u64)(0xFFFFFFFFu - (u32)(cbase + k3));
    u64 key4 = ((u64)q4 << 32) | (u64)(0xFFFFFFFFu - (u32)(cbase + k4));
    if (q1 && key1 > bk) bk = key1;    // ascending k order: smaller i wins ties via ~i
    if (q2 && key2 > bk) bk = key2;
    if (q3 && key3 > bk) bk = key3;
    if (q4 && key4 > bk) bk = key4;
  }

  // ---- phase B: lane = anchor; threefry + rank values ----
  int i = cbase + lane;
  bool pc = (pcbits >> lane) & 1ull;
  bool nc = (ncbits >> lane) & 1ull;
  u32 rp = 0, rn = 0;
  if (pcbits){                    // wave-uniform skip (pos is rare)
    u32 a0,a1;
    tf2x32(keys.k[b][0], keys.k[b][1], 0u, (u32)i, a0,a1);
    rp = pc ? ((a0^a1) >> 9) + 1u : 0u;
  }
  if (ncbits){
    u32 c0,c1;
    tf2x32(keys.k[b][2], keys.k[b][3], 0u, (u32)i, c0,c1);
    rn = nc ? ((c0^c1) >> 9) + 1u : 0u;
  }
  rpv[b*NN_+i] = rp;
  rnv[b*NN_+i] = rn;

  // ---- per-block combine + plain coalesced stores (no atomics, no pre-zero) ----
  __shared__ u64 wl[128];
  __shared__ u32 scnt[4];
  wl[wid*64 + lane] = bk;
  if (lane == 0){
    scnt[wid*2+0] = (u32)__popcll(pcbits);
    scnt[wid*2+1] = (u32)__popcll(ncbits);
  }
  __syncthreads();
  if (tid < 64){
    u64 m0 = wl[tid], m1 = wl[64+tid];
    bestpart[((size_t)(b*NBLK_ + bx))*64 + tid] = m0 > m1 ? m0 : m1;
  }
  if (tid == 0){
    cnts_part[(b*NBLK_ + bx)*2 + 0] = scnt[0] + scnt[2];
    cnts_part[(b*NBLK_ + bx)*2 + 1] = scnt[1] + scnt[3];
  }
}

// ---------------- K2: fused reduce + forced fixup + selection threshold ----------------
__global__ __launch_bounds__(1024) void k_selfix(const float* __restrict__ x,
                                                 const u64* __restrict__ bestpart,
                                                 const u32* __restrict__ cnts_part,
                                                 Keys keys,
                                                 u32* __restrict__ rpv,
                                                 const u32* __restrict__ rnv,
                                                 u32* __restrict__ selp){
  #pragma clang fp contract(off)
  int cls = blockIdx.x, b = blockIdx.y, tid = threadIdx.x;
  int lane = tid & 63, wid = tid >> 6;   // 16 waves
  int id = b*2 + cls;

  __shared__ float gbox[MM_][4];
  __shared__ float ga[MM_];
  __shared__ u64 red[16][64];
  __shared__ u32 scp[16], scn[16];
  __shared__ u32 fist[64];
  __shared__ float fmx[16][64];
  __shared__ u32 sq[4];
  __shared__ u32 hist[4096];
  __shared__ u32 ts[1024];
  __shared__ u32 wt[16], wsuf[16];
  __shared__ u32 bc[2];
  __shared__ u64 L[512];
  __shared__ u32 lc;

  // gt boxes + areas
  if (tid < 256) gbox[tid>>2][tid&3] = x[(b*MM_ + (tid>>2))*XROW_ + 21 + (tid&3)];
  __syncthreads();
  if (tid < MM_){
    float g0=gbox[tid][0], g1=gbox[tid][1], g2=gbox[tid][2], g3=gbox[tid][3];
    ga[tid] = (g2-g0)*(g3-g1);
  }

  // bestpart reduce (16-way parallel over parts)
  u64 m = 0;
  for (int blk = wid; blk < NBLK_; blk += 16){
    u64 v = bestpart[((size_t)(b*NBLK_ + blk))*64 + lane];
    if (v > m) m = v;
  }
  red[wid][lane] = m;

  // candidate count sums
  u32 cp = 0, cn = 0;
  if (tid < NBLK_){ cp = cnts_part[(b*NBLK_+tid)*2+0]; cn = cnts_part[(b*NBLK_+tid)*2+1]; }
  #pragma unroll
  for (int off = 32; off >= 1; off >>= 1){
    cp += (u32)__shfl_xor((int)cp, off, 64);
    cn += (u32)__shfl_xor((int)cn, off, 64);
  }
  if (lane == 0){ scp[wid] = cp; scn[wid] = cn; }
  __syncthreads();

  if (tid < 64){
    u64 mm = red[0][tid];
    #pragma unroll
    for (int w = 1; w < 16; ++w){ u64 v = red[w][tid]; if (v > mm) mm = v; }
    fist[tid] = ((u32)(mm >> 32) != 0u) ? (0xFFFFFFFFu - (u32)mm) : 0xFFFFFFFFu;
  }
  if (tid == 0){
    u32 c0 = 0, c1 = 0;
    for (int w = 0; w < 16; ++w){ c0 += scp[w]; c1 += scn[w]; }
    sq[0] = c0; sq[1] = c1;
  }
  __syncthreads();

  // forced pcflag recompute: was forced anchor already a pos candidate?
  {
    int j = tid & 63, q = tid >> 6;
    float mm = 0.0f;
    u32 fi = fist[j];
    if (fi != 0xFFFFFFFFu){
      float ax1,ay1,ax2,ay2;
      anchor_from((int)(fi % 9), (int)(fi / 9), ax1,ay1,ax2,ay2);
      float aarea = (ax2-ax1)*(ay2-ay1);
      #pragma unroll
      for (int t = 0; t < 4; ++t){
        int j2 = q*4 + t;
        float iou = iou_of(ax1,ay1,ax2,ay2,aarea,
                           gbox[j2][0],gbox[j2][1],gbox[j2][2],gbox[j2][3], ga[j2]);
        mm = fmaxf(mm, iou);
      }
    }
    fmx[q][j] = mm;
  }
  __syncthreads();

  if (tid < 64){
    int j = tid;
    u32 fi = fist[j];
    bool valid = (fi != 0xFFFFFFFFu);
    float mm = fmx[0][j];
    #pragma unroll
    for (int q = 1; q < 16; ++q) mm = fmaxf(mm, fmx[q][j]);
    bool wasc = (mm > 0.7f);                 // == (rpv[fi] != 0 pre-fixup), bit-exact
    bool first = true;
    for (int j2 = 0; j2 < j; ++j2) if (fist[j2] == fi) first = false;
    bool add = valid && !wasc && first;
    u64 bal = __ballot(add);
    if (cls == 0 && valid){                  // pos block: ensure forced anchor in rpv
      u32 a0,a1; tf2x32(keys.k[b][0], keys.k[b][1], 0u, fi, a0,a1);
      rpv[(size_t)b*NN_ + fi] = ((a0^a1) >> 9) + 1u;   // idempotent value
    }
    if (tid == 0) sq[2] = sq[0] + (u32)__popcll(bal);  // posc
  }
  __syncthreads();

  u32 posc = sq[2], negc = sq[1];
  u32 npos = min(posc, POS_CAP_);
  u32 K   = cls ? (BATCH_ - npos) : npos;
  u32 cnt = cls ? negc : posc;
  if (cnt <= K){
    if (tid == 0){ selp[id*2+0] = 0u; selp[id*2+1] = 0xFFFFFFFFu; }
    return;
  }

  const u32* v = (cls ? rnv : rpv) + (size_t)b*NN_;
  const uint4* v4 = (const uint4*)v;
  #pragma unroll
  for (int h = 0; h < 4; ++h) hist[h*1024 + tid] = 0;
  if (tid == 0) lc = 0;
  __syncthreads();
  // pass 1: LDS histogram of high 12 bits of (v-1)
  for (int i2 = tid; i2 < NN_/4; i2 += 1024){
    uint4 q = v4[i2];
    if (q.x) atomicAdd(&hist[(q.x-1u)>>11], 1u);
    if (q.y) atomicAdd(&hist[(q.y-1u)>>11], 1u);
    if (q.z) atomicAdd(&hist[(q.z-1u)>>11], 1u);
    if (q.w) atomicAdd(&hist[(q.w-1u)>>11], 1u);
  }
  __syncthreads();
  u32 s = hist[tid*4+0] + hist[tid*4+1] + hist[tid*4+2] + hist[tid*4+3];
  ts[tid] = s;
  u32 incl = s;
  #pragma unroll
  for (int off = 1; off < 64; off <<= 1){
    u32 o = (u32)__shfl_down((int)incl, off, 64);
    incl += (lane + off < 64) ? o : 0u;
  }
  if (lane == 0) wt[wid] = incl;             // wave total
  __syncthreads();
  if (tid < 16){ u32 ss = 0; for (int w = tid+1; w < 16; ++w) ss += wt[w]; wsuf[tid] = ss; }
  __syncthreads();
  u32 excl = incl - s + wsuf[wid];           // count in strictly-higher chunks
  if (excl < K && excl + s >= K){
    u32 acc = excl;
    for (int q = 3; q >= 0; --q){
      u32 h = hist[tid*4 + q];
      if (acc + h >= K){ bc[0] = (u32)(tid*4 + q); bc[1] = K - acc; break; }
      acc += h;
    }
  }
  __syncthreads();
  u32 B = bc[0], Kp = bc[1];
  // pass 2: collect bin-B members
  for (int i2 = tid; i2 < NN_/4; i2 += 1024){
    uint4 q = v4[i2];
    #pragma unroll
    for (int c = 0; c < 4; ++c){
      u32 xv = (c==0)?q.x:(c==1)?q.y:(c==2)?q.z:q.w;
      if (xv && ((xv - 1u) >> 11) == B){
        u32 p = atomicAdd(&lc, 1u);
        if (p < 512u) L[p] = ((u64)xv << 32) | (u32)(i2*4 + c);
      }
    }
  }
  __syncthreads();
  u32 n = min(lc, 512u);
  if (tid < (int)n){
    u64 me = L[tid]; u32 mv = (u32)(me >> 32), mi = (u32)me;
    u32 r = 0;
    for (u32 t2 = 0; t2 < n; ++t2){
      u64 o = L[t2]; u32 ov = (u32)(o >> 32), oi = (u32)o;
      r += (ov > mv) || (ov == mv && oi < mi);
    }
    if (r == Kp - 1u){ selp[id*2+0] = mv; selp[id*2+1] = mi; }
  }
}

// ---------------- K3: final cls + offsets (argmax recomputed for selpos only) ----------------
__global__ __launch_bounds__(256) void k_out(const float* __restrict__ x,
                                             const u32* __restrict__ rpv,
                                             const u32* __restrict__ rnv,
                                             const u32* __restrict__ selp,
                                             float* __restrict__ out){
  #pragma clang fp contract(off)
  int b = blockIdx.y, tid = threadIdx.x;
  __shared__ float g[MM_][4];
  g[tid>>2][tid&3] = x[b*MM_*XROW_ + (tid>>2)*XROW_ + 21 + (tid&3)];
  __syncthreads();
  int i = blockIdx.x*256 + tid;
  if (i >= NN_) return;

  u32 pth = selp[(b*2+0)*2+0], pcut = selp[(b*2+0)*2+1];
  u32 nth = selp[(b*2+1)*2+0], ncut = selp[(b*2+1)*2+1];
  u32 pv = rpv[b*NN_+i], nv = rnv[b*NN_+i];
  bool selpos = (pv > 0u) && (pv > pth || (pv == pth && (u32)i <= pcut));
  bool selneg = (nv > 0u) && (nv > nth || (nv == nth && (u32)i <= ncut));
  float cls = selpos ? 1.0f : -1.0f;
  if (selneg) cls = 0.0f;

  float tx = 0.0f, ty = 0.0f, tw = 0.0f, th = 0.0f;
  if (selpos){
    int a = i % 9, cell = i / 9;
    float ax1,ay1,ax2,ay2;
    anchor_from(a, cell, ax1,ay1,ax2,ay2);
    float area_a = (ax2-ax1)*(ay2-ay1);
    float best = -1.0f; int bj = 0;
    for (int j = 0; j < MM_; ++j){
      float g0=g[j][0], g1=g[j][1], g2=g[j][2], g3=g[j][3];
      float ix1 = fmaxf(ax1,g0), iy1 = fmaxf(ay1,g1);
      float ix2 = fminf(ax2,g2), iy2 = fminf(ay2,g3);
      float iw = fmaxf(ix2-ix1, 0.0f), ih = fmaxf(iy2-iy1, 0.0f);
      float inter = iw*ih;
      float den = area_a + (g2-g0)*(g3-g1);
      den = den - inter;
      den = den + 1e-7f;
      float iou = inter / den;
      if (iou > best){ best = iou; bj = j; }
    }
    float g0=g[bj][0], g1=g[bj][1], g2=g[bj][2], g3=g[bj][3];
    float wgt = g2-g0, hgt = g3-g1;
    float xcg = (g2+g0)*0.5f, ycg = (g3+g1)*0.5f;
    float wr = ax2-ax1, hr = ay2-ay1;
    float xcr = (ax2+ax1)*0.5f, ycr = (ay2+ay1)*0.5f;
    float wrs = (wr > 0.0f) ? wr : 1.0f;
    float hrs = (hr > 0.0f) ? hr : 1.0f;
    tx = (wgt > 0.0f) ? (xcg - xcr)/wrs : 0.0f;
    ty = (hgt > 0.0f) ? (ycg - ycr)/hrs : 0.0f;
    tw = (wgt > 0.0f) ? logf(wgt/wrs) : 0.0f;
    th = (hgt > 0.0f) ? logf(hgt/hrs) : 0.0f;
  }
  float* o = out + (size_t)(b*NN_+i)*5;
  o[0] = cls; o[1] = tx; o[2] = ty; o[3] = tw; o[4] = th;
}

extern "C" void kernel_launch(void* const* d_in, const int* in_sizes, int n_in,
                              void* d_out, int out_size, void* d_ws, size_t ws_size,
                              hipStream_t stream) {
  const float* x = (const float*)d_in[0];
  float* out = (float*)d_out;
  char* ws = (char*)d_ws;

  // ws layout — nothing needs pre-zeroing (all buffers fully overwritten each launch)
  u32* selp      = (u32*)(ws + 0);            // 256 B   (k_selfix writes all)
  u64* bestpart  = (u64*)(ws + 512);          // 16*225*64*8 = 1,843,200 B
  u32* cnts_part = (u32*)(ws + 1843712);      // 16*225*2*4 = 28,800 B
  u32* rpv       = (u32*)(ws + 1872640);      // 1,843,200 B
  u32* rnv       = (u32*)(ws + 3715840);      // 1,843,200 B (end ≈ 5.56 MB)
  (void)ws_size; (void)in_sizes; (void)n_in; (void)out_size;

  // host-side JAX key derivation (partitionable threefry), deterministic
  Keys keys;
  for (int b = 0; b < BB_; ++b){
    u32 r0, r1;
    tf2x32(0u, 42u, 0u, (u32)b, r0, r1);
    tf2x32(r0, r1, 0u, 0u, keys.k[b][0], keys.k[b][1]);
    tf2x32(r0, r1, 0u, 1u, keys.k[b][2], keys.k[b][3]);
  }

  k_main  <<<dim3(NBLK_, BB_), 128, 0, stream>>>(x, keys, bestpart, cnts_part, rpv, rnv);
  k_selfix<<<dim3(2, BB_), 1024, 0, stream>>>(x, bestpart, cnts_part, keys, rpv, rnv, selp);
  k_out   <<<dim3(113, BB_), 256, 0, stream>>>(x, rpv, rnv, selp, out);
}

// Round 10
// 71.138 us; speedup vs baseline: 2.2243x; 1.0555x over previous
//
#include <hip/hip_runtime.h>
#include <stdint.h>
#include <math.h>

typedef unsigned int u32;
typedef unsigned long long u64;

#define NN_ 28800
#define MM_ 64
#define BB_ 16
#define XROW_ 25
#define POS_CAP_ 128u
#define BATCH_ 256u
#define NBLK_ 75                  // k_main blocks per image (384 anchors each)
#define XSPAN_ 1579               // floats staged per image row: [21, 1600)

struct Keys { u32 k[BB_][4]; };

// ---------------- threefry2x32 (JAX-exact), host+device ----------------
__host__ __device__ __forceinline__ u32 rotl32(u32 v, u32 r){ return (v<<r)|(v>>(32u-r)); }

__host__ __device__ __forceinline__ void tf2x32(u32 k0, u32 k1, u32 x0, u32 x1, u32& y0, u32& y1){
  u32 ks2 = k0 ^ k1 ^ 0x1BD11BDAu;
  x0 += k0; x1 += k1;
#define TFR(r) { x0 += x1; x1 = rotl32(x1,(r)); x1 ^= x0; }
  TFR(13) TFR(15) TFR(26) TFR(6)   x0 += k1;  x1 += ks2 + 1u;
  TFR(17) TFR(29) TFR(16) TFR(24)  x0 += ks2; x1 += k0  + 2u;
  TFR(13) TFR(15) TFR(26) TFR(6)   x0 += k0;  x1 += k1  + 3u;
  TFR(17) TFR(29) TFR(16) TFR(24)  x0 += k1;  x1 += ks2 + 4u;
  TFR(13) TFR(15) TFR(26) TFR(6)   x0 += ks2; x1 += k0  + 5u;
#undef TFR
  y0 = x0; y1 = x1;
}

// ---------------- anchors: pure-float, bit-exact vs numpy ----------------
__device__ __forceinline__ void anchor_from(int a, int cell,
                                            float& ox1, float& oy1, float& ox2, float& oy2){
  #pragma clang fp contract(off)
  int w = cell & 63;
  int h = cell >> 6;
  int p = (a >= 6) ? 2 : ((a >= 3) ? 1 : 0);
  int q = a - p*3;
  float sf = (p==0) ? 128.0f : ((p==1) ? 256.0f : 512.0f);
  const float SQH = 0.70710678118654752440f;
  const float SQ2 = 1.41421356237309514547f;
  float cw = (q==0) ? SQH : ((q==1) ? 1.0f : SQ2);
  float ch = (q==0) ? SQ2 : ((q==1) ? 1.0f : SQH);
  float hx = (sf*cw) * 0.5f;
  float hy = (sf*ch) * 0.5f;
  float cx = ((float)w + 0.5f) * 16.0f;
  float cy = ((float)h + 0.5f) * 16.0f;
  float X1 = (cx - hx) / 1024.0f;
  float Y1 = (cy - hy) / 800.0f;
  float X2 = (cx + hx) / 1024.0f;
  float Y2 = (cy + hy) / 800.0f;
  bool valid = (X1 > 0.0f) && (Y1 > 0.0f) && (X2 < 1.0f) && (Y2 < 1.0f);
  ox1 = valid ? X1 : 0.0f;
  oy1 = valid ? Y1 : 0.0f;
  ox2 = valid ? X2 : 0.0f;
  oy2 = valid ? Y2 : 0.0f;
}

__device__ __forceinline__ float rdlane(float v, int k){
  return __int_as_float(__builtin_amdgcn_readlane(__float_as_int(v), k));
}

__device__ __forceinline__ float iou_of(float bx1,float by1,float bx2,float by2,float ba,
                                        float gx1,float gy1,float gx2,float gy2,float garea){
  #pragma clang fp contract(off)
  float ix1 = fmaxf(bx1,gx1), iy1 = fmaxf(by1,gy1);
  float ix2 = fminf(bx2,gx2), iy2 = fminf(by2,gy2);
  float iw = fmaxf(ix2-ix1, 0.0f), ih = fmaxf(iy2-iy1, 0.0f);
  float inter = iw*ih;
  float den = ba + garea;        // exact reference op order, no FMA
  den = den - inter;
  den = den + 1e-7f;
  return inter / den;
}

// ---------------- K1: transposed (lane = gt); coalesced x staging; 6 waves/block ----------------
__global__ __launch_bounds__(384) void k_main(const float* __restrict__ x, Keys keys,
                                              u64* __restrict__ bestpart,
                                              u32* __restrict__ cnts_part,
                                              u32* __restrict__ rpv, u32* __restrict__ rnv){
  #pragma clang fp contract(off)
  int tid = threadIdx.x;          // 0..383 (6 waves)
  int lane = tid & 63;
  int wid = tid >> 6;
  int bx = blockIdx.x;
  int b = blockIdx.y;
  int cbase = (bx*6 + wid)*64;    // this wave's 64-anchor chunk

  __shared__ float xr[XSPAN_];    // x[b, :, 21:1600) -> gt j coord c at xr[25j+c]
  for (int t = tid; t < XSPAN_; t += 384) xr[t] = x[b*(MM_*XROW_) + 21 + t];
  __syncthreads();

  // lane j holds gt j in registers (conflict-free: 25*j mod 32 all distinct)
  float gx1 = xr[25*lane+0], gy1 = xr[25*lane+1], gx2 = xr[25*lane+2], gy2 = xr[25*lane+3];
  float garea = (gx2-gx1)*(gy2-gy1);

  // lane k holds anchor (cbase+k)'s box
  int ia = cbase + lane;
  int a = ia % 9, cell = ia / 9;
  float ax1,ay1,ax2,ay2;
  anchor_from(a, cell, ax1,ay1,ax2,ay2);
  float aarea = (ax2-ax1)*(ay2-ay1);

  u64 valid_mask = __ballot(ax2 > 0.0f);
  u64 pcbits = 0;
  u64 ncbits = ~valid_mask;       // invalid anchors: miou==0 -> neg cand, not pos
  u64 bk = 0;                     // per-lane: best (iou,~i) for gt=lane

  u64 vm = valid_mask;
  while (vm){
    int k1 = __ffsll((unsigned long long)vm) - 1; vm &= vm - 1ull;
    int k2 = vm ? __ffsll((unsigned long long)vm) - 1 : k1; vm &= vm - 1ull;
    int k3 = vm ? __ffsll((unsigned long long)vm) - 1 : k1; vm &= vm - 1ull;
    int k4 = vm ? __ffsll((unsigned long long)vm) - 1 : k1; vm &= vm - 1ull;
    // four independent chains -> ILP (duplicates are idempotent)
    float c1x1=rdlane(ax1,k1), c1y1=rdlane(ay1,k1), c1x2=rdlane(ax2,k1), c1y2=rdlane(ay2,k1), c1a=rdlane(aarea,k1);
    float c2x1=rdlane(ax1,k2), c2y1=rdlane(ay1,k2), c2x2=rdlane(ax2,k2), c2y2=rdlane(ay2,k2), c2a=rdlane(aarea,k2);
    float c3x1=rdlane(ax1,k3), c3y1=rdlane(ay1,k3), c3x2=rdlane(ax2,k3), c3y2=rdlane(ay2,k3), c3a=rdlane(aarea,k3);
    float c4x1=rdlane(ax1,k4), c4y1=rdlane(ay1,k4), c4x2=rdlane(ax2,k4), c4y2=rdlane(ay2,k4), c4a=rdlane(aarea,k4);
    float i1 = iou_of(c1x1,c1y1,c1x2,c1y2,c1a, gx1,gy1,gx2,gy2,garea);
    float i2 = iou_of(c2x1,c2y1,c2x2,c2y2,c2a, gx1,gy1,gx2,gy2,garea);
    float i3 = iou_of(c3x1,c3y1,c3x2,c3y2,c3a, gx1,gy1,gx2,gy2,garea);
    float i4 = iou_of(c4x1,c4y1,c4x2,c4y2,c4a, gx1,gy1,gx2,gy2,garea);
    u64 p1 = __ballot(i1 > 0.7f), n1 = __ballot(i1 >= 0.3f);
    u64 p2 = __ballot(i2 > 0.7f), n2 = __ballot(i2 >= 0.3f);
    u64 p3 = __ballot(i3 > 0.7f), n3 = __ballot(i3 >= 0.3f);
    u64 p4 = __ballot(i4 > 0.7f), n4 = __ballot(i4 >= 0.3f);
    if (p1)  pcbits |= 1ull << k1;
    if (!n1) ncbits |= 1ull << k1;
    if (p2)  pcbits |= 1ull << k2;
    if (!n2) ncbits |= 1ull << k2;
    if (p3)  pcbits |= 1ull << k3;
    if (!n3) ncbits |= 1ull << k3;
    if (p4)  pcbits |= 1ull << k4;
    if (!n4) ncbits |= 1ull << k4;
    u32 q1 = __float_as_uint(i1), q2 = __float_as_uint(i2);
    u32 q3 = __float_as_uint(i3), q4 = __float_as_uint(i4);
    u64 key1 = ((u64)q1 << 32) | (u64)(0xFFFFFFFFu - (u32)(cbase + k1));
    u64 key2 = ((u64)q2 << 32) | (u64)(0xFFFFFFFFu - (u32)(cbase + k2));
    u64 key3 = ((u64)q3 << 32) | (u64)(0xFFFFFFFFu - (u32)(cbase + k3));
    u64 key4 = ((u64)q4 << 32) | (u64)(0xFFFFFFFFu - (u32)(cbase + k4));
    if (q1 && key1 > bk) bk = key1;    // ascending k order: smaller i wins ties via ~i
    if (q2 && key2 > bk) bk = key2;
    if (q3 && key3 > bk) bk = key3;
    if (q4 && key4 > bk) bk = key4;
  }

  // ---- phase B: lane = anchor; threefry + rank values ----
  int i = cbase + lane;
  bool pc = (pcbits >> lane) & 1ull;
  bool nc = (ncbits >> lane) & 1ull;
  u32 rp = 0, rn = 0;
  if (pcbits){                    // wave-uniform skip (pos is rare)
    u32 a0,a1;
    tf2x32(keys.k[b][0], keys.k[b][1], 0u, (u32)i, a0,a1);
    rp = pc ? ((a0^a1) >> 9) + 1u : 0u;
  }
  if (ncbits){
    u32 c0,c1;
    tf2x32(keys.k[b][2], keys.k[b][3], 0u, (u32)i, c0,c1);
    rn = nc ? ((c0^c1) >> 9) + 1u : 0u;
  }
  rpv[b*NN_+i] = rp;
  rnv[b*NN_+i] = rn;

  // ---- per-block combine + plain coalesced stores (no atomics, no pre-zero) ----
  __shared__ u64 wl[384];
  __shared__ u32 scnt[12];
  wl[wid*64 + lane] = bk;
  if (lane == 0){
    scnt[wid*2+0] = (u32)__popcll(pcbits);
    scnt[wid*2+1] = (u32)__popcll(ncbits);
  }
  __syncthreads();
  if (tid < 64){
    u64 m = wl[tid];
    #pragma unroll
    for (int w = 1; w < 6; ++w){ u64 v = wl[w*64+tid]; if (v > m) m = v; }
    bestpart[((size_t)(b*NBLK_ + bx))*64 + tid] = m;
  }
  if (tid == 0){
    u32 c0 = 0, c1 = 0;
    #pragma unroll
    for (int w = 0; w < 6; ++w){ c0 += scnt[w*2+0]; c1 += scnt[w*2+1]; }
    cnts_part[(b*NBLK_ + bx)*2 + 0] = c0;
    cnts_part[(b*NBLK_ + bx)*2 + 1] = c1;
  }
}

// ---------------- K2: fused reduce + forced fixup + selection threshold ----------------
__global__ __launch_bounds__(1024) void k_selfix(const float* __restrict__ x,
                                                 const u64* __restrict__ bestpart,
                                                 const u32* __restrict__ cnts_part,
                                                 Keys keys,
                                                 u32* __restrict__ rpv,
                                                 const u32* __restrict__ rnv,
                                                 u32* __restrict__ selp){
  #pragma clang fp contract(off)
  int cls = blockIdx.x, b = blockIdx.y, tid = threadIdx.x;
  int lane = tid & 63, wid = tid >> 6;   // 16 waves
  int id = b*2 + cls;

  __shared__ float gbox[MM_][4];
  __shared__ float ga[MM_];
  __shared__ u64 red[16][64];
  __shared__ u32 scp[16], scn[16];
  __shared__ u32 fist[64];
  __shared__ float fmx[16][64];
  __shared__ u32 sq[4];
  __shared__ u32 hist[4096];
  __shared__ u32 wt[16], wsuf[16];
  __shared__ u32 bc[2];
  __shared__ u64 L[512];
  __shared__ u32 lc;

  // gt boxes + areas
  if (tid < 256) gbox[tid>>2][tid&3] = x[(b*MM_ + (tid>>2))*XROW_ + 21 + (tid&3)];
  __syncthreads();
  if (tid < MM_){
    float g0=gbox[tid][0], g1=gbox[tid][1], g2=gbox[tid][2], g3=gbox[tid][3];
    ga[tid] = (g2-g0)*(g3-g1);
  }

  // bestpart reduce (16-way parallel over parts)
  u64 m = 0;
  for (int blk = wid; blk < NBLK_; blk += 16){
    u64 v = bestpart[((size_t)(b*NBLK_ + blk))*64 + lane];
    if (v > m) m = v;
  }
  red[wid][lane] = m;

  // candidate count sums
  u32 cp = 0, cn = 0;
  if (tid < NBLK_){ cp = cnts_part[(b*NBLK_+tid)*2+0]; cn = cnts_part[(b*NBLK_+tid)*2+1]; }
  #pragma unroll
  for (int off = 32; off >= 1; off >>= 1){
    cp += (u32)__shfl_xor((int)cp, off, 64);
    cn += (u32)__shfl_xor((int)cn, off, 64);
  }
  if (lane == 0){ scp[wid] = cp; scn[wid] = cn; }
  __syncthreads();

  if (tid < 64){
    u64 mm = red[0][tid];
    #pragma unroll
    for (int w = 1; w < 16; ++w){ u64 v = red[w][tid]; if (v > mm) mm = v; }
    fist[tid] = ((u32)(mm >> 32) != 0u) ? (0xFFFFFFFFu - (u32)mm) : 0xFFFFFFFFu;
  }
  if (tid == 0){
    u32 c0 = 0, c1 = 0;
    for (int w = 0; w < 16; ++w){ c0 += scp[w]; c1 += scn[w]; }
    sq[0] = c0; sq[1] = c1;
  }
  __syncthreads();

  // forced pcflag recompute: was forced anchor already a pos candidate?
  {
    int j = tid & 63, q = tid >> 6;
    float mm = 0.0f;
    u32 fi = fist[j];
    if (fi != 0xFFFFFFFFu){
      float ax1,ay1,ax2,ay2;
      anchor_from((int)(fi % 9), (int)(fi / 9), ax1,ay1,ax2,ay2);
      float aarea = (ax2-ax1)*(ay2-ay1);
      #pragma unroll
      for (int t = 0; t < 4; ++t){
        int j2 = q*4 + t;
        float iou = iou_of(ax1,ay1,ax2,ay2,aarea,
                           gbox[j2][0],gbox[j2][1],gbox[j2][2],gbox[j2][3], ga[j2]);
        mm = fmaxf(mm, iou);
      }
    }
    fmx[q][j] = mm;
  }
  __syncthreads();

  if (tid < 64){
    int j = tid;
    u32 fi = fist[j];
    bool valid = (fi != 0xFFFFFFFFu);
    float mm = fmx[0][j];
    #pragma unroll
    for (int q = 1; q < 16; ++q) mm = fmaxf(mm, fmx[q][j]);
    bool wasc = (mm > 0.7f);                 // == (rpv[fi] != 0 pre-fixup), bit-exact
    bool first = true;
    for (int j2 = 0; j2 < j; ++j2) if (fist[j2] == fi) first = false;
    bool add = valid && !wasc && first;
    u64 bal = __ballot(add);
    if (cls == 0 && valid){                  // pos block: ensure forced anchor in rpv
      u32 a0,a1; tf2x32(keys.k[b][0], keys.k[b][1], 0u, fi, a0,a1);
      rpv[(size_t)b*NN_ + fi] = ((a0^a1) >> 9) + 1u;   // idempotent value
    }
    if (tid == 0) sq[2] = sq[0] + (u32)__popcll(bal);  // posc
  }
  __syncthreads();

  u32 posc = sq[2], negc = sq[1];
  u32 npos = min(posc, POS_CAP_);
  u32 K   = cls ? (BATCH_ - npos) : npos;
  u32 cnt = cls ? negc : posc;
  if (cnt <= K){
    if (tid == 0){ selp[id*2+0] = 0u; selp[id*2+1] = 0xFFFFFFFFu; }
    return;
  }

  const u32* v = (cls ? rnv : rpv) + (size_t)b*NN_;
  const uint4* v4 = (const uint4*)v;
  #pragma unroll
  for (int h = 0; h < 4; ++h) hist[h*1024 + tid] = 0;
  if (tid == 0) lc = 0;
  __syncthreads();
  // pass 1: LDS histogram of high 12 bits of (v-1)
  for (int i2 = tid; i2 < NN_/4; i2 += 1024){
    uint4 q = v4[i2];
    if (q.x) atomicAdd(&hist[(q.x-1u)>>11], 1u);
    if (q.y) atomicAdd(&hist[(q.y-1u)>>11], 1u);
    if (q.z) atomicAdd(&hist[(q.z-1u)>>11], 1u);
    if (q.w) atomicAdd(&hist[(q.w-1u)>>11], 1u);
  }
  __syncthreads();
  u32 s = hist[tid*4+0] + hist[tid*4+1] + hist[tid*4+2] + hist[tid*4+3];
  u32 incl = s;
  #pragma unroll
  for (int off = 1; off < 64; off <<= 1){
    u32 o = (u32)__shfl_down((int)incl, off, 64);
    incl += (lane + off < 64) ? o : 0u;
  }
  if (lane == 0) wt[wid] = incl;             // wave total
  __syncthreads();
  if (tid < 16){ u32 ss = 0; for (int w = tid+1; w < 16; ++w) ss += wt[w]; wsuf[tid] = ss; }
  __syncthreads();
  u32 excl = incl - s + wsuf[wid];           // count in strictly-higher chunks
  if (excl < K && excl + s >= K){
    u32 acc = excl;
    for (int q = 3; q >= 0; --q){
      u32 h = hist[tid*4 + q];
      if (acc + h >= K){ bc[0] = (u32)(tid*4 + q); bc[1] = K - acc; break; }
      acc += h;
    }
  }
  __syncthreads();
  u32 B = bc[0], Kp = bc[1];
  // pass 2: collect bin-B members
  for (int i2 = tid; i2 < NN_/4; i2 += 1024){
    uint4 q = v4[i2];
    #pragma unroll
    for (int c = 0; c < 4; ++c){
      u32 xv = (c==0)?q.x:(c==1)?q.y:(c==2)?q.z:q.w;
      if (xv && ((xv - 1u) >> 11) == B){
        u32 p = atomicAdd(&lc, 1u);
        if (p < 512u) L[p] = ((u64)xv << 32) | (u32)(i2*4 + c);
      }
    }
  }
  __syncthreads();
  u32 n = min(lc, 512u);
  if (tid < (int)n){
    u64 me = L[tid]; u32 mv = (u32)(me >> 32), mi = (u32)me;
    u32 r = 0;
    for (u32 t2 = 0; t2 < n; ++t2){
      u64 o = L[t2]; u32 ov = (u32)(o >> 32), oi = (u32)o;
      r += (ov > mv) || (ov == mv && oi < mi);
    }
    if (r == Kp - 1u){ selp[id*2+0] = mv; selp[id*2+1] = mi; }
  }
}

// ---------------- K3: final cls + offsets (coalesced x staging; argmax for selpos only) ----------------
__global__ __launch_bounds__(256) void k_out(const float* __restrict__ x,
                                             const u32* __restrict__ rpv,
                                             const u32* __restrict__ rnv,
                                             const u32* __restrict__ selp,
                                             float* __restrict__ out){
  #pragma clang fp contract(off)
  int b = blockIdx.y, tid = threadIdx.x;
  __shared__ float xr[XSPAN_];    // gt j coord c at xr[25j+c]
  for (int t = tid; t < XSPAN_; t += 256) xr[t] = x[b*(MM_*XROW_) + 21 + t];
  __syncthreads();
  int i = blockIdx.x*256 + tid;
  if (i >= NN_) return;

  u32 pth = selp[(b*2+0)*2+0], pcut = selp[(b*2+0)*2+1];
  u32 nth = selp[(b*2+1)*2+0], ncut = selp[(b*2+1)*2+1];
  u32 pv = rpv[b*NN_+i], nv = rnv[b*NN_+i];
  bool selpos = (pv > 0u) && (pv > pth || (pv == pth && (u32)i <= pcut));
  bool selneg = (nv > 0u) && (nv > nth || (nv == nth && (u32)i <= ncut));
  float cls = selpos ? 1.0f : -1.0f;
  if (selneg) cls = 0.0f;

  float tx = 0.0f, ty = 0.0f, tw = 0.0f, th = 0.0f;
  if (selpos){
    int a = i % 9, cell = i / 9;
    float ax1,ay1,ax2,ay2;
    anchor_from(a, cell, ax1,ay1,ax2,ay2);
    float area_a = (ax2-ax1)*(ay2-ay1);
    float best = -1.0f; int bj = 0;
    for (int j = 0; j < MM_; ++j){
      float g0=xr[25*j+0], g1=xr[25*j+1], g2=xr[25*j+2], g3=xr[25*j+3];  // broadcast
      float ix1 = fmaxf(ax1,g0), iy1 = fmaxf(ay1,g1);
      float ix2 = fminf(ax2,g2), iy2 = fminf(ay2,g3);
      float iw = fmaxf(ix2-ix1, 0.0f), ih = fmaxf(iy2-iy1, 0.0f);
      float inter = iw*ih;
      float den = area_a + (g2-g0)*(g3-g1);
      den = den - inter;
      den = den + 1e-7f;
      float iou = inter / den;
      if (iou > best){ best = iou; bj = j; }
    }
    float g0=xr[25*bj+0], g1=xr[25*bj+1], g2=xr[25*bj+2], g3=xr[25*bj+3];
    float wgt = g2-g0, hgt = g3-g1;
    float xcg = (g2+g0)*0.5f, ycg = (g3+g1)*0.5f;
    float wr = ax2-ax1, hr = ay2-ay1;
    float xcr = (ax2+ax1)*0.5f, ycr = (ay2+ay1)*0.5f;
    float wrs = (wr > 0.0f) ? wr : 1.0f;
    float hrs = (hr > 0.0f) ? hr : 1.0f;
    tx = (wgt > 0.0f) ? (xcg - xcr)/wrs : 0.0f;
    ty = (hgt > 0.0f) ? (ycg - ycr)/hrs : 0.0f;
    tw = (wgt > 0.0f) ? logf(wgt/wrs) : 0.0f;
    th = (hgt > 0.0f) ? logf(hgt/hrs) : 0.0f;
  }
  float* o = out + (size_t)(b*NN_+i)*5;
  o[0] = cls; o[1] = tx; o[2] = ty; o[3] = tw; o[4] = th;
}

extern "C" void kernel_launch(void* const* d_in, const int* in_sizes, int n_in,
                              void* d_out, int out_size, void* d_ws, size_t ws_size,
                              hipStream_t stream) {
  const float* x = (const float*)d_in[0];
  float* out = (float*)d_out;
  char* ws = (char*)d_ws;

  // ws layout — nothing needs pre-zeroing (all buffers fully overwritten each launch)
  u32* selp      = (u32*)(ws + 0);            // 256 B   (k_selfix writes all)
  u64* bestpart  = (u64*)(ws + 512);          // 16*75*64*8 = 614,400 B
  u32* cnts_part = (u32*)(ws + 614912);       // 16*75*2*4 = 9,600 B
  u32* rpv       = (u32*)(ws + 624640);       // 1,843,200 B
  u32* rnv       = (u32*)(ws + 2467840);      // 1,843,200 B (end ≈ 4.31 MB)
  (void)ws_size; (void)in_sizes; (void)n_in; (void)out_size;

  // host-side JAX key derivation (partitionable threefry), deterministic
  Keys keys;
  for (int b = 0; b < BB_; ++b){
    u32 r0, r1;
    tf2x32(0u, 42u, 0u, (u32)b, r0, r1);
    tf2x32(r0, r1, 0u, 0u, keys.k[b][0], keys.k[b][1]);
    tf2x32(r0, r1, 0u, 1u, keys.k[b][2], keys.k[b][3]);
  }

  k_main  <<<dim3(NBLK_, BB_), 384, 0, stream>>>(x, keys, bestpart, cnts_part, rpv, rnv);
  k_selfix<<<dim3(2, BB_), 1024, 0, stream>>>(x, bestpart, cnts_part, keys, rpv, rnv, selp);
  k_out   <<<dim3(113, BB_), 256, 0, stream>>>(x, rpv, rnv, selp, out);
}